// Round 1
// baseline (2185.827 us; speedup 1.0000x reference)
//
#include <hip/hip_runtime.h>
#include <hip/hip_bf16.h>
#include <cstdint>
#include <cstddef>

// Problem constants
// B=2, S=2048, D=1024, R=64, H=16, DH=64, N=32; BS = B*S = 4096

// ---------------------------------------------------------------------------
// GEMM: C[M,N] = A[M,K] @ B[K,N]; tiles 128x128, BK=16, 256 threads, 8x8/thread
// MODE 0 (project): A standard row-major [M,K]; B[k][j] = F[j>>6][k][j&63]
//                   (F is f_qk/f_v with dims [N=32, D=K, R=64])
// MODE 1 (restore): A[i][k] = h[i][k&63] * W[i][k>>6]   (h [M,64], W [M,32]);
//                   B standard row-major [K,N] (r_qk/r_v flat is [N*R, D])
// MODE 2 (outproj): A standard; B[k][j] = Wo[j*K + k]   (transposed read)
// ---------------------------------------------------------------------------
template<int MODE>
__global__ __launch_bounds__(256) void gemm_kernel(const float* __restrict__ A,
                                                   const float* __restrict__ B,
                                                   const float* __restrict__ W,
                                                   float* __restrict__ C,
                                                   int M, int N, int K)
{
    __shared__ float As[16][132];   // [k][m], +4 pad
    __shared__ float Bs[16][132];   // [k][n], +4 pad
    const int tid  = threadIdx.x;
    const int row0 = blockIdx.y * 128;
    const int col0 = blockIdx.x * 128;
    const int tx = tid & 15, ty = tid >> 4;

    float acc[8][8];
#pragma unroll
    for (int i = 0; i < 8; ++i)
#pragma unroll
        for (int j = 0; j < 8; ++j) acc[i][j] = 0.f;

    for (int k0 = 0; k0 < K; k0 += 16) {
        // ---- A tile: 128 rows x 16 k, stored transposed As[k][m] ----
#pragma unroll
        for (int t = 0; t < 2; ++t) {
            int id = tid + t * 256;      // 0..511 float4 slots
            int ar = id >> 2;            // 0..127 row
            int ac = (id & 3) * 4;       // 0,4,8,12 k-offset
            float4 v;
            if (MODE == 1) {
                int nb = k0 >> 6;        // constant within BK=16 tile
                const float* hp = A + (size_t)(row0 + ar) * 64 + (k0 & 63) + ac;
                float4 hv = *(const float4*)hp;
                float  wv = W[(size_t)(row0 + ar) * 32 + nb];
                v = make_float4(hv.x * wv, hv.y * wv, hv.z * wv, hv.w * wv);
            } else {
                v = *(const float4*)(A + (size_t)(row0 + ar) * K + k0 + ac);
            }
            As[ac + 0][ar] = v.x; As[ac + 1][ar] = v.y;
            As[ac + 2][ar] = v.z; As[ac + 3][ar] = v.w;
        }
        // ---- B tile: 16 k x 128 cols ----
#pragma unroll
        for (int t = 0; t < 2; ++t) {
            int id = tid + t * 256;
            if (MODE == 2) {
                int jr = id >> 2;            // 0..127 col (= output feature o)
                int kc = (id & 3) * 4;       // k offset
                float4 v = *(const float4*)(B + (size_t)(col0 + jr) * K + k0 + kc);
                Bs[kc + 0][jr] = v.x; Bs[kc + 1][jr] = v.y;
                Bs[kc + 2][jr] = v.z; Bs[kc + 3][jr] = v.w;
            } else {
                int br = id >> 5;            // 0..15 k row
                int bc = (id & 31) * 4;      // col offset 0..124
                const float* bp;
                if (MODE == 0) {
                    int j = col0 + bc;       // j%64 in {0..60}, float4 stays in-block
                    bp = B + (size_t)(j >> 6) * K * 64 + (size_t)(k0 + br) * 64 + (j & 63);
                } else {
                    bp = B + (size_t)(k0 + br) * N + col0 + bc;
                }
                float4 v = *(const float4*)bp;
                *(float4*)&Bs[br][bc] = v;
            }
        }
        __syncthreads();
#pragma unroll
        for (int kk = 0; kk < 16; ++kk) {
            float a[8], b[8];
            *(float4*)&a[0] = *(const float4*)&As[kk][ty * 8];
            *(float4*)&a[4] = *(const float4*)&As[kk][ty * 8 + 4];
            *(float4*)&b[0] = *(const float4*)&Bs[kk][tx * 8];
            *(float4*)&b[4] = *(const float4*)&Bs[kk][tx * 8 + 4];
#pragma unroll
            for (int i = 0; i < 8; ++i)
#pragma unroll
                for (int j = 0; j < 8; ++j)
                    acc[i][j] = fmaf(a[i], b[j], acc[i][j]);
        }
        __syncthreads();
    }
#pragma unroll
    for (int i = 0; i < 8; ++i) {
        size_t r = (size_t)(row0 + ty * 8 + i);
        *(float4*)(C + r * N + col0 + tx * 8)     = make_float4(acc[i][0], acc[i][1], acc[i][2], acc[i][3]);
        *(float4*)(C + r * N + col0 + tx * 8 + 4) = make_float4(acc[i][4], acc[i][5], acc[i][6], acc[i][7]);
    }
}

// ---------------------------------------------------------------------------
// Mix: h1[bs,r] = sum_n w1[bs,n] * P[bs, n*64+r]  (and optionally h2 with w2)
// ---------------------------------------------------------------------------
__global__ __launch_bounds__(256) void mix_kernel(const float* __restrict__ P,
                                                  const float* __restrict__ w1,
                                                  const float* __restrict__ w2,
                                                  float* __restrict__ h1,
                                                  float* __restrict__ h2,
                                                  int two)
{
    int tid = blockIdx.x * 256 + threadIdx.x;   // BS*64 threads total
    int bs = tid >> 6;
    int r  = tid & 63;
    const float* Pp = P + (size_t)bs * 2048 + r;
    float a = 0.f, b = 0.f;
#pragma unroll
    for (int n = 0; n < 32; ++n) {
        float p = Pp[n * 64];
        a = fmaf(w1[bs * 32 + n], p, a);
        if (two) b = fmaf(w2[bs * 32 + n], p, b);
    }
    h1[tid] = a;
    if (two) h2[tid] = b;
}

// ---------------------------------------------------------------------------
// Causal flash attention, fp32. Q-tile=64, K-tile=32, one block per (qtile, b*h).
// Layouts: QsT/KsT transposed [d][m]; Vs [n][dh]; Ss [m][n].
// ---------------------------------------------------------------------------
__global__ __launch_bounds__(256) void flash_kernel(const float* __restrict__ Q,
                                                    const float* __restrict__ Km,
                                                    const float* __restrict__ Vm,
                                                    float* __restrict__ O)
{
    const int S = 2048, D = 1024;
    const int bh = blockIdx.y;
    const int b  = bh >> 4, h = bh & 15;
    const int q0 = blockIdx.x * 64;
    const int tid = threadIdx.x;

    __shared__ float QsT[64][68];
    __shared__ float KsT[64][36];
    __shared__ float Vs[32][68];
    __shared__ float Ss[64][36];
    __shared__ float row_m[64], row_l[64], row_a[64];

    const float* Qbase = Q + ((size_t)(b * S + q0)) * D + h * 64;
#pragma unroll
    for (int t = 0; t < 4; ++t) {
        int id = tid + t * 256;          // 0..1023 float4 slots
        int mr = id >> 4;                // 0..63
        int dc = (id & 15) * 4;
        float4 v = *(const float4*)(Qbase + (size_t)mr * D + dc);
        QsT[dc + 0][mr] = v.x; QsT[dc + 1][mr] = v.y;
        QsT[dc + 2][mr] = v.z; QsT[dc + 3][mr] = v.w;
    }
    if (tid < 64) { row_m[tid] = -3.0e38f; row_l[tid] = 0.f; }

    float o[4][4];
#pragma unroll
    for (int i = 0; i < 4; ++i)
#pragma unroll
        for (int j = 0; j < 4; ++j) o[i][j] = 0.f;

    const int nkt = 2 * blockIdx.x + 2;      // causal: keys up to q0+63
    for (int kt = 0; kt < nkt; ++kt) {
        const int k0 = kt * 32;
        __syncthreads();                      // prior iter done; safe to overwrite
        // load K (transposed) + V tiles: 32 rows x 64 dh
#pragma unroll
        for (int t = 0; t < 2; ++t) {
            int id = tid + t * 256;          // 0..511
            int nr = id >> 4;                // 0..31
            int dc = (id & 15) * 4;
            size_t grow = ((size_t)(b * S + k0 + nr)) * D + h * 64 + dc;
            float4 kv = *(const float4*)(Km + grow);
            KsT[dc + 0][nr] = kv.x; KsT[dc + 1][nr] = kv.y;
            KsT[dc + 2][nr] = kv.z; KsT[dc + 3][nr] = kv.w;
            *(float4*)&Vs[nr][dc] = *(const float4*)(Vm + grow);
        }
        __syncthreads();
        // scores: 64x32, each thread 2 rows x 4 cols
        {
            const int m0 = (tid >> 3) * 2;
            const int n0 = (tid & 7) * 4;
            float s[2][4];
#pragma unroll
            for (int i = 0; i < 2; ++i)
#pragma unroll
                for (int j = 0; j < 4; ++j) s[i][j] = 0.f;
#pragma unroll 8
            for (int d = 0; d < 64; ++d) {
                float2 qa = *(const float2*)&QsT[d][m0];
                float4 kb = *(const float4*)&KsT[d][n0];
                s[0][0] = fmaf(qa.x, kb.x, s[0][0]);
                s[0][1] = fmaf(qa.x, kb.y, s[0][1]);
                s[0][2] = fmaf(qa.x, kb.z, s[0][2]);
                s[0][3] = fmaf(qa.x, kb.w, s[0][3]);
                s[1][0] = fmaf(qa.y, kb.x, s[1][0]);
                s[1][1] = fmaf(qa.y, kb.y, s[1][1]);
                s[1][2] = fmaf(qa.y, kb.z, s[1][2]);
                s[1][3] = fmaf(qa.y, kb.w, s[1][3]);
            }
            const float scale = 0.125f;    // 1/sqrt(64)
            const bool diag = (k0 + 31 > q0);
#pragma unroll
            for (int i = 0; i < 2; ++i) {
                float4 v;
                float* pv = (float*)&v;
#pragma unroll
                for (int j = 0; j < 4; ++j) {
                    float val = s[i][j] * scale;
                    if (diag && (k0 + n0 + j > q0 + m0 + i)) val = -3.0e38f;
                    pv[j] = val;
                }
                *(float4*)&Ss[m0 + i][n0] = v;
            }
        }
        __syncthreads();
        // online-softmax stats, one thread per row
        if (tid < 64) {
            const int r = tid;
            float om = row_m[r];
            float mx = om;
#pragma unroll 8
            for (int i = 0; i < 32; ++i) mx = fmaxf(mx, Ss[r][i]);
            float al = __expf(om - mx);
            float sm = 0.f;
#pragma unroll 8
            for (int i = 0; i < 32; ++i) {
                float e = __expf(Ss[r][i] - mx);
                Ss[r][i] = e;
                sm += e;
            }
            row_l[r] = row_l[r] * al + sm;
            row_m[r] = mx;
            row_a[r] = al;
        }
        __syncthreads();
        // O = O*alpha + P@V; each thread 4 rows x 4 dh
        {
            const int m0  = (tid >> 4) * 4;
            const int dh0 = (tid & 15) * 4;
            float al[4] = { row_a[m0], row_a[m0 + 1], row_a[m0 + 2], row_a[m0 + 3] };
#pragma unroll
            for (int i = 0; i < 4; ++i)
#pragma unroll
                for (int j = 0; j < 4; ++j) o[i][j] *= al[i];
#pragma unroll 8
            for (int n = 0; n < 32; ++n) {
                float4 vb = *(const float4*)&Vs[n][dh0];
#pragma unroll
                for (int i = 0; i < 4; ++i) {
                    float p = Ss[m0 + i][n];
                    o[i][0] = fmaf(p, vb.x, o[i][0]);
                    o[i][1] = fmaf(p, vb.y, o[i][1]);
                    o[i][2] = fmaf(p, vb.z, o[i][2]);
                    o[i][3] = fmaf(p, vb.w, o[i][3]);
                }
            }
        }
    }
    __syncthreads();
    {
        const int m0  = (tid >> 4) * 4;
        const int dh0 = (tid & 15) * 4;
#pragma unroll
        for (int i = 0; i < 4; ++i) {
            float inv = 1.0f / row_l[m0 + i];
            float4 v = make_float4(o[i][0] * inv, o[i][1] * inv, o[i][2] * inv, o[i][3] * inv);
            *(float4*)(O + ((size_t)(b * S + q0 + m0 + i)) * D + h * 64 + dh0) = v;
        }
    }
}

// ---------------------------------------------------------------------------
extern "C" void kernel_launch(void* const* d_in, const int* in_sizes, int n_in,
                              void* d_out, int out_size, void* d_ws, size_t ws_size,
                              hipStream_t stream)
{
    const float* x     = (const float*)d_in[0];
    const float* wfqkQ = (const float*)d_in[1];
    const float* wfqkK = (const float*)d_in[2];
    const float* wfv   = (const float*)d_in[3];
    const float* wrqkQ = (const float*)d_in[4];
    const float* wrqkK = (const float*)d_in[5];
    const float* wrv   = (const float*)d_in[6];
    const float* f_qk  = (const float*)d_in[7];
    const float* f_v   = (const float*)d_in[8];
    const float* r_qk  = (const float*)d_in[9];
    const float* r_v   = (const float*)d_in[10];
    const float* W_O   = (const float*)d_in[11];
    float* out = (float*)d_out;

    // workspace layout (floats): peak ~104 MB
    float* ws  = (float*)d_ws;
    float* P   = ws;                               // 4096*2048 (reused for P_qk then P_v)
    float* h_q = P   + (size_t)4096 * 2048;        // 4096*64
    float* h_k = h_q + (size_t)4096 * 64;
    float* h_v = h_k + (size_t)4096 * 64;
    float* Qm  = h_v + (size_t)4096 * 64;          // 4096*1024
    float* Km  = Qm  + (size_t)4096 * 1024;
    float* Vm  = Km  + (size_t)4096 * 1024;
    float* Am  = Vm  + (size_t)4096 * 1024;        // attention output

    dim3 blk(256);

    // P_qk = X @ F_qk  -> h_q, h_k
    gemm_kernel<0><<<dim3(16, 32), blk, 0, stream>>>(x, f_qk, nullptr, P, 4096, 2048, 1024);
    mix_kernel<<<dim3(1024), blk, 0, stream>>>(P, wfqkQ, wfqkK, h_q, h_k, 1);
    // P_v = X @ F_v    -> h_v
    gemm_kernel<0><<<dim3(16, 32), blk, 0, stream>>>(x, f_v, nullptr, P, 4096, 2048, 1024);
    mix_kernel<<<dim3(1024), blk, 0, stream>>>(P, wfv, nullptr, h_v, nullptr, 0);
    // restore GEMMs: Q/K/V = (h (x) w) @ Rmat
    gemm_kernel<1><<<dim3(8, 32), blk, 0, stream>>>(h_q, r_qk, wrqkQ, Qm, 4096, 1024, 2048);
    gemm_kernel<1><<<dim3(8, 32), blk, 0, stream>>>(h_k, r_qk, wrqkK, Km, 4096, 1024, 2048);
    gemm_kernel<1><<<dim3(8, 32), blk, 0, stream>>>(h_v, r_v,  wrv,  Vm, 4096, 1024, 2048);
    // causal SDPA
    flash_kernel<<<dim3(32, 32), blk, 0, stream>>>(Qm, Km, Vm, Am);
    // out = A @ W_O^T
    gemm_kernel<2><<<dim3(8, 32), blk, 0, stream>>>(Am, W_O, nullptr, out, 4096, 1024, 1024);
}

// Round 2
// 1121.999 us; speedup vs baseline: 1.9482x; 1.9482x over previous
//
#include <hip/hip_runtime.h>
#include <hip/hip_bf16.h>
#include <cstdint>
#include <cstddef>

// B=2, S=2048, D=1024, R=64, H=16, DH=64, N=32; BS=4096
typedef unsigned short u16;
typedef short bfrag __attribute__((ext_vector_type(8)));     // 8 bf16 = 4 VGPRs
typedef float f32x4 __attribute__((ext_vector_type(4)));
typedef u16 u16x8 __attribute__((ext_vector_type(8)));

__device__ __forceinline__ u16 f2bf(float v) {
    union { float f; unsigned u; } a; a.f = v;
    unsigned r = a.u + 0x7fff + ((a.u >> 16) & 1);   // RNE
    return (u16)(r >> 16);
}
__device__ __forceinline__ float bf2f(u16 u) {
    union { unsigned u; float f; } a; a.u = ((unsigned)u) << 16;
    return a.f;
}
__device__ __forceinline__ f32x4 mfma_bf16(bfrag a, bfrag b, f32x4 c) {
    return __builtin_amdgcn_mfma_f32_16x16x32_bf16(a, b, c, 0, 0, 0);
}
__device__ __forceinline__ void async_copy16(const void* g, void* l) {
    __builtin_amdgcn_global_load_lds(
        (const __attribute__((address_space(1))) unsigned*)g,
        (__attribute__((address_space(3))) unsigned*)l, 16, 0, 0);
}

// ---------------------------------------------------------------------------
// elementwise cast fp32 -> bf16 hi (+lo if SPLIT); n4 = count/4
// ---------------------------------------------------------------------------
template<int SPLIT>
__global__ __launch_bounds__(256) void cast_split(const float* __restrict__ s,
                                                  u16* __restrict__ dh,
                                                  u16* __restrict__ dl, int n4)
{
    int i = blockIdx.x * 256 + threadIdx.x;
    if (i >= n4) return;
    float4 v = ((const float4*)s)[i];
    float vv[4] = {v.x, v.y, v.z, v.w};
    ushort4 h, l;
    u16* hp = (u16*)&h; u16* lp = (u16*)&l;
#pragma unroll
    for (int e = 0; e < 4; ++e) {
        u16 hb = f2bf(vv[e]);
        hp[e] = hb;
        if (SPLIT) lp[e] = f2bf(vv[e] - bf2f(hb));
    }
    ((ushort4*)dh)[i] = h;
    if (SPLIT) ((ushort4*)dl)[i] = l;
}

// ---------------------------------------------------------------------------
// transpose + cast: dst[z*C + c][r] = src[z*R*C + r*C + c]; dst pitch = dpitch
// ---------------------------------------------------------------------------
template<int SPLIT>
__global__ __launch_bounds__(256) void transpose_cast(const float* __restrict__ src,
                                                      u16* __restrict__ dh,
                                                      u16* __restrict__ dl,
                                                      int R, int C, int dpitch)
{
    __shared__ float t[32][33];
    int z = blockIdx.z;
    const float* s = src + (size_t)z * R * C;
    int r0 = blockIdx.y * 32, c0 = blockIdx.x * 32;
    int tx = threadIdx.x & 31, ty = threadIdx.x >> 5;
#pragma unroll
    for (int p = 0; p < 4; ++p)
        t[ty + p * 8][tx] = s[(size_t)(r0 + ty + p * 8) * C + c0 + tx];
    __syncthreads();
#pragma unroll
    for (int p = 0; p < 4; ++p) {
        int rr = ty + p * 8;
        float v = t[tx][rr];
        size_t di = (size_t)(z * C + c0 + rr) * dpitch + r0 + tx;
        u16 hb = f2bf(v);
        dh[di] = hb;
        if (SPLIT) dl[di] = f2bf(v - bf2f(hb));
    }
}

// ---------------------------------------------------------------------------
// MFMA GEMM: C[M,N] = A[M,K] @ BT[N,K]^T, 128x128 tile, BK=32, 4 waves.
// LDS granule g (16B = 8 bf16) of row r stored at slot r*4 + (g ^ ((r>>1)&3)).
// SPLIT: hi/lo bf16 operands, 3 MFMAs (AhBh + AhBl + AlBh) ~ fp32 precision.
// AMODE 0: A from pre-cast bf16 arrays (global_load_lds)
// AMODE 1: A[i][k] = h[i][k&63] * w[i][k>>6], split on the fly (fp32 sources)
// AMODE 2: A fp32 [M][K], cast to bf16 on the fly (single)
// ---------------------------------------------------------------------------
template<int SPLIT, int AMODE>
__global__ __launch_bounds__(256) void gemm_mfma(const u16* __restrict__ Agh,
                                                 const u16* __restrict__ Agl,
                                                 const float* __restrict__ hA,
                                                 const float* __restrict__ wA,
                                                 const u16* __restrict__ Bgh,
                                                 const u16* __restrict__ Bgl,
                                                 float* __restrict__ C,
                                                 int M, int N, int K)
{
    constexpr int NBUF = SPLIT ? 4 : 2;
    __shared__ u16 lds[NBUF * 4096];
    u16* Ath = lds;
    u16* Atl = SPLIT ? (lds + 4096) : lds;
    u16* Bth = lds + (SPLIT ? 8192 : 4096);
    u16* Btl = SPLIT ? (lds + 12288) : lds;

    const int tid  = threadIdx.x;
    const int lane = tid & 63;
    const int wv   = tid >> 6;
    const int q    = lane >> 4;
    const int tn   = lane & 15;
    const int wm   = (wv >> 1) * 64;
    const int wn   = (wv & 1) * 64;
    const int row0 = blockIdx.y * 128;
    const int col0 = blockIdx.x * 128;
    const int wbase = (tid & 192) * 8;   // wave-uniform LDS offset (u16 units)

    f32x4 acc[4][4];
#pragma unroll
    for (int i = 0; i < 4; ++i)
#pragma unroll
        for (int j = 0; j < 4; ++j) acc[i][j] = 0.f;

    for (int k0 = 0; k0 < K; k0 += 32) {
        // ---- stage B (always async) ----
#pragma unroll
        for (int shot = 0; shot < 2; ++shot) {
            int G = tid + shot * 256;
            int row = G >> 2, kgs = G & 3;
            int kgg = kgs ^ ((row >> 1) & 3);
            size_t goff = (size_t)(col0 + row) * K + k0 + kgg * 8;
            async_copy16(Bgh + goff, Bth + shot * 2048 + wbase);
            if (SPLIT) async_copy16(Bgl + goff, Btl + shot * 2048 + wbase);
        }
        // ---- stage A ----
        if (AMODE == 0) {
#pragma unroll
            for (int shot = 0; shot < 2; ++shot) {
                int G = tid + shot * 256;
                int row = G >> 2, kgs = G & 3;
                int kgg = kgs ^ ((row >> 1) & 3);
                size_t goff = (size_t)(row0 + row) * K + k0 + kgg * 8;
                async_copy16(Agh + goff, Ath + shot * 2048 + wbase);
                if (SPLIT) async_copy16(Agl + goff, Atl + shot * 2048 + wbase);
            }
        } else {
            const int r = tid >> 1;
            float wmul = (AMODE == 1) ? wA[(size_t)(row0 + r) * 32 + (k0 >> 6)] : 0.f;
#pragma unroll
            for (int gi = 0; gi < 2; ++gi) {
                int gg = (tid & 1) * 2 + gi;
                const float* sp = (AMODE == 1)
                    ? hA + (size_t)(row0 + r) * 64 + (k0 & 63) + gg * 8
                    : hA + (size_t)(row0 + r) * K + k0 + gg * 8;
                float4 v0 = *(const float4*)sp;
                float4 v1 = *(const float4*)(sp + 4);
                float vv[8] = {v0.x, v0.y, v0.z, v0.w, v1.x, v1.y, v1.z, v1.w};
                u16x8 hi, lo;
#pragma unroll
                for (int e = 0; e < 8; ++e) {
                    float val = (AMODE == 1) ? vv[e] * wmul : vv[e];
                    u16 hb = f2bf(val);
                    hi[e] = hb;
                    if (SPLIT) lo[e] = f2bf(val - bf2f(hb));
                }
                int slot = r * 4 + (gg ^ ((r >> 1) & 3));
                *(u16x8*)(Ath + slot * 8) = hi;
                if (SPLIT) *(u16x8*)(Atl + slot * 8) = lo;
            }
        }
        __syncthreads();

        bfrag ah[4], bh[4], al[4], bl[4];
#pragma unroll
        for (int i = 0; i < 4; ++i) {
            int m = wm + i * 16 + tn;
            int g = m * 4 + (q ^ ((m >> 1) & 3));
            ah[i] = *(const bfrag*)(Ath + g * 8);
            if (SPLIT) al[i] = *(const bfrag*)(Atl + g * 8);
        }
#pragma unroll
        for (int j = 0; j < 4; ++j) {
            int n = wn + j * 16 + tn;
            int g = n * 4 + (q ^ ((n >> 1) & 3));
            bh[j] = *(const bfrag*)(Bth + g * 8);
            if (SPLIT) bl[j] = *(const bfrag*)(Btl + g * 8);
        }
#pragma unroll
        for (int i = 0; i < 4; ++i)
#pragma unroll
            for (int j = 0; j < 4; ++j) {
                acc[i][j] = mfma_bf16(ah[i], bh[j], acc[i][j]);
                if (SPLIT) {
                    acc[i][j] = mfma_bf16(ah[i], bl[j], acc[i][j]);
                    acc[i][j] = mfma_bf16(al[i], bh[j], acc[i][j]);
                }
            }
        __syncthreads();
    }

    // epilogue: C/D layout col=lane&15, row=(lane>>4)*4+reg  [m89-verified]
#pragma unroll
    for (int i = 0; i < 4; ++i)
#pragma unroll
        for (int j = 0; j < 4; ++j)
#pragma unroll
            for (int rg = 0; rg < 4; ++rg) {
                int row = row0 + wm + i * 16 + q * 4 + rg;
                int col = col0 + wn + j * 16 + tn;
                C[(size_t)row * N + col] = acc[i][j][rg];
            }
}

// ---------------------------------------------------------------------------
// Mix: h1[bs,r] = sum_n w1[bs,n] * P[bs, n*64+r]  (optionally h2 with w2)
// ---------------------------------------------------------------------------
__global__ __launch_bounds__(256) void mix_kernel(const float* __restrict__ P,
                                                  const float* __restrict__ w1,
                                                  const float* __restrict__ w2,
                                                  float* __restrict__ h1,
                                                  float* __restrict__ h2,
                                                  int two)
{
    int tid = blockIdx.x * 256 + threadIdx.x;
    int bs = tid >> 6;
    int r  = tid & 63;
    const float* Pp = P + (size_t)bs * 2048 + r;
    float a = 0.f, b = 0.f;
#pragma unroll
    for (int n = 0; n < 32; ++n) {
        float p = Pp[n * 64];
        a = fmaf(w1[bs * 32 + n], p, a);
        if (two) b = fmaf(w2[bs * 32 + n], p, b);
    }
    h1[tid] = a;
    if (two) h2[tid] = b;
}

// ---------------------------------------------------------------------------
// Causal flash attention, fp32. Q-tile=64, K-tile=32.
// R2: heavy blocks first, 4-way parallel softmax, QsT pitch 66.
// ---------------------------------------------------------------------------
__global__ __launch_bounds__(256) void flash_kernel(const float* __restrict__ Q,
                                                    const float* __restrict__ Km,
                                                    const float* __restrict__ Vm,
                                                    float* __restrict__ O)
{
    const int S = 2048, D = 1024;
    const int bh = blockIdx.y;
    const int b  = bh >> 4, h = bh & 15;
    const int q0 = (31 - blockIdx.x) * 64;     // heaviest tiles launch first
    const int tid = threadIdx.x;

    __shared__ float QsT[64][66];
    __shared__ float KsT[64][36];
    __shared__ float Vs[32][68];
    __shared__ float Ss[64][36];
    __shared__ float row_m[64], row_l[64], row_a[64];
    __shared__ float pmax[4][64], psum[4][64];

    const float* Qbase = Q + ((size_t)(b * S + q0)) * D + h * 64;
#pragma unroll
    for (int t = 0; t < 4; ++t) {
        int id = tid + t * 256;
        int mr = id >> 4;
        int dc = (id & 15) * 4;
        float4 v = *(const float4*)(Qbase + (size_t)mr * D + dc);
        QsT[dc + 0][mr] = v.x; QsT[dc + 1][mr] = v.y;
        QsT[dc + 2][mr] = v.z; QsT[dc + 3][mr] = v.w;
    }
    if (tid < 64) { row_m[tid] = -3.0e38f; row_l[tid] = 0.f; }

    float o[4][4];
#pragma unroll
    for (int i = 0; i < 4; ++i)
#pragma unroll
        for (int j = 0; j < 4; ++j) o[i][j] = 0.f;

    const int nkt = (q0 >> 5) + 2;
    for (int kt = 0; kt < nkt; ++kt) {
        const int k0 = kt * 32;
        __syncthreads();
#pragma unroll
        for (int t = 0; t < 2; ++t) {
            int id = tid + t * 256;
            int nr = id >> 4;
            int dc = (id & 15) * 4;
            size_t grow = ((size_t)(b * S + k0 + nr)) * D + h * 64 + dc;
            float4 kv = *(const float4*)(Km + grow);
            KsT[dc + 0][nr] = kv.x; KsT[dc + 1][nr] = kv.y;
            KsT[dc + 2][nr] = kv.z; KsT[dc + 3][nr] = kv.w;
            *(float4*)&Vs[nr][dc] = *(const float4*)(Vm + grow);
        }
        __syncthreads();
        // scores 64x32: each thread 2 rows x 4 cols
        {
            const int m0 = (tid >> 3) * 2;
            const int n0 = (tid & 7) * 4;
            float s[2][4];
#pragma unroll
            for (int i = 0; i < 2; ++i)
#pragma unroll
                for (int j = 0; j < 4; ++j) s[i][j] = 0.f;
#pragma unroll 8
            for (int d = 0; d < 64; ++d) {
                float2 qa = *(const float2*)&QsT[d][m0];
                float4 kb = *(const float4*)&KsT[d][n0];
                s[0][0] = fmaf(qa.x, kb.x, s[0][0]);
                s[0][1] = fmaf(qa.x, kb.y, s[0][1]);
                s[0][2] = fmaf(qa.x, kb.z, s[0][2]);
                s[0][3] = fmaf(qa.x, kb.w, s[0][3]);
                s[1][0] = fmaf(qa.y, kb.x, s[1][0]);
                s[1][1] = fmaf(qa.y, kb.y, s[1][1]);
                s[1][2] = fmaf(qa.y, kb.z, s[1][2]);
                s[1][3] = fmaf(qa.y, kb.w, s[1][3]);
            }
            const float scale = 0.125f;
            const bool diag = (k0 + 31 > q0);
#pragma unroll
            for (int i = 0; i < 2; ++i) {
                float4 v;
                float* pv = (float*)&v;
#pragma unroll
                for (int j = 0; j < 4; ++j) {
                    float val = s[i][j] * scale;
                    if (diag && (k0 + n0 + j > q0 + m0 + i)) val = -3.0e38f;
                    pv[j] = val;
                }
                *(float4*)&Ss[m0 + i][n0] = v;
            }
        }
        __syncthreads();
        // parallel online-softmax: 4 segments of 8 cols per row
        {
            const int sr = tid & 63, sg = tid >> 6;
            float mx = -3.0e38f;
#pragma unroll
            for (int c = 0; c < 8; ++c) mx = fmaxf(mx, Ss[sr][sg * 8 + c]);
            pmax[sg][sr] = mx;
            __syncthreads();
            float om = row_m[sr];
            float nm = fmaxf(fmaxf(pmax[0][sr], pmax[1][sr]),
                             fmaxf(pmax[2][sr], pmax[3][sr]));
            nm = fmaxf(nm, om);
            float sm = 0.f;
#pragma unroll
            for (int c = 0; c < 8; ++c) {
                float e = __expf(Ss[sr][sg * 8 + c] - nm);
                Ss[sr][sg * 8 + c] = e;
                sm += e;
            }
            psum[sg][sr] = sm;
            __syncthreads();
            if (sg == 0) {
                float s4 = psum[0][sr] + psum[1][sr] + psum[2][sr] + psum[3][sr];
                float al = __expf(om - nm);
                row_l[sr] = row_l[sr] * al + s4;
                row_m[sr] = nm;
                row_a[sr] = al;
            }
        }
        __syncthreads();
        // O = O*alpha + P@V
        {
            const int m0  = (tid >> 4) * 4;
            const int dh0 = (tid & 15) * 4;
            float al[4] = { row_a[m0], row_a[m0 + 1], row_a[m0 + 2], row_a[m0 + 3] };
#pragma unroll
            for (int i = 0; i < 4; ++i)
#pragma unroll
                for (int j = 0; j < 4; ++j) o[i][j] *= al[i];
#pragma unroll 8
            for (int n = 0; n < 32; ++n) {
                float4 vb = *(const float4*)&Vs[n][dh0];
#pragma unroll
                for (int i = 0; i < 4; ++i) {
                    float p = Ss[m0 + i][n];
                    o[i][0] = fmaf(p, vb.x, o[i][0]);
                    o[i][1] = fmaf(p, vb.y, o[i][1]);
                    o[i][2] = fmaf(p, vb.z, o[i][2]);
                    o[i][3] = fmaf(p, vb.w, o[i][3]);
                }
            }
        }
    }
    __syncthreads();
    {
        const int m0  = (tid >> 4) * 4;
        const int dh0 = (tid & 15) * 4;
#pragma unroll
        for (int i = 0; i < 4; ++i) {
            float inv = 1.0f / row_l[m0 + i];
            float4 v = make_float4(o[i][0] * inv, o[i][1] * inv, o[i][2] * inv, o[i][3] * inv);
            *(float4*)(O + ((size_t)(b * S + q0 + m0 + i)) * D + h * 64 + dh0) = v;
        }
    }
}

// ---------------------------------------------------------------------------
extern "C" void kernel_launch(void* const* d_in, const int* in_sizes, int n_in,
                              void* d_out, int out_size, void* d_ws, size_t ws_size,
                              hipStream_t stream)
{
    const float* x     = (const float*)d_in[0];
    const float* wfqkQ = (const float*)d_in[1];
    const float* wfqkK = (const float*)d_in[2];
    const float* wfv   = (const float*)d_in[3];
    const float* wrqkQ = (const float*)d_in[4];
    const float* wrqkK = (const float*)d_in[5];
    const float* wrv   = (const float*)d_in[6];
    const float* f_qk  = (const float*)d_in[7];
    const float* f_v   = (const float*)d_in[8];
    const float* r_qk  = (const float*)d_in[9];
    const float* r_v   = (const float*)d_in[10];
    const float* W_O   = (const float*)d_in[11];
    float* out = (float*)d_out;

    const size_t MB = 1u << 20;
    char* w8 = (char*)d_ws;
    u16*  WOb   = (u16*)(w8 + 0);          //  2MB [1024][1024]
    u16*  FqkTh = (u16*)(w8 + 2  * MB);    //  4MB [2048][1024]
    u16*  FqkTl = (u16*)(w8 + 6  * MB);
    u16*  FvT   = (u16*)(w8 + 10 * MB);
    u16*  RqkTh = (u16*)(w8 + 14 * MB);    //  4MB [1024][2048]
    u16*  RqkTl = (u16*)(w8 + 18 * MB);
    u16*  RvT   = (u16*)(w8 + 22 * MB);
    float* h_q  = (float*)(w8 + 26 * MB);  //  1MB each
    float* h_k  = (float*)(w8 + 27 * MB);
    float* h_v  = (float*)(w8 + 28 * MB);
    float* P    = (float*)(w8 + 32 * MB);  // 32MB [4096][2048]
    float* Qf   = (float*)(w8 + 32 * MB);  // 16MB (over P, after mix)
    float* Kf   = (float*)(w8 + 48 * MB);
    u16*  x_hi  = (u16*)(w8 + 64 * MB);    //  8MB
    u16*  x_lo  = (u16*)(w8 + 72 * MB);
    float* Vf   = (float*)(w8 + 64 * MB);  // 16MB (over x, after projections)
    float* Am   = (float*)(w8 + 80 * MB);  // 16MB -> total 96MB

    dim3 blk(256);

    // casts / transposes
    cast_split<1><<<dim3(4096), blk, 0, stream>>>(x, x_hi, x_lo, 1024 * 1024);
    cast_split<0><<<dim3(1024), blk, 0, stream>>>(W_O, WOb, nullptr, 256 * 1024);
    transpose_cast<1><<<dim3(2, 32, 32), blk, 0, stream>>>(f_qk, FqkTh, FqkTl, 1024, 64, 1024);
    transpose_cast<0><<<dim3(2, 32, 32), blk, 0, stream>>>(f_v,  FvT,   nullptr, 1024, 64, 1024);
    transpose_cast<1><<<dim3(32, 64, 1), blk, 0, stream>>>(r_qk, RqkTh, RqkTl, 2048, 1024, 2048);
    transpose_cast<0><<<dim3(32, 64, 1), blk, 0, stream>>>(r_v,  RvT,   nullptr, 2048, 1024, 2048);

    // project + mix
    gemm_mfma<1, 0><<<dim3(16, 32), blk, 0, stream>>>(x_hi, x_lo, nullptr, nullptr,
                                                      FqkTh, FqkTl, P, 4096, 2048, 1024);
    mix_kernel<<<dim3(1024), blk, 0, stream>>>(P, wfqkQ, wfqkK, h_q, h_k, 1);
    gemm_mfma<0, 0><<<dim3(16, 32), blk, 0, stream>>>(x_hi, nullptr, nullptr, nullptr,
                                                      FvT, nullptr, P, 4096, 2048, 1024);
    mix_kernel<<<dim3(1024), blk, 0, stream>>>(P, wfv, nullptr, h_v, nullptr, 0);

    // restore (Q,K split; V single)
    gemm_mfma<1, 1><<<dim3(8, 32), blk, 0, stream>>>(nullptr, nullptr, h_q, wrqkQ,
                                                     RqkTh, RqkTl, Qf, 4096, 1024, 2048);
    gemm_mfma<1, 1><<<dim3(8, 32), blk, 0, stream>>>(nullptr, nullptr, h_k, wrqkK,
                                                     RqkTh, RqkTl, Kf, 4096, 1024, 2048);
    gemm_mfma<0, 1><<<dim3(8, 32), blk, 0, stream>>>(nullptr, nullptr, h_v, wrv,
                                                     RvT, nullptr, Vf, 4096, 1024, 2048);

    // attention + output projection
    flash_kernel<<<dim3(32, 32), blk, 0, stream>>>(Qf, Kf, Vf, Am);
    gemm_mfma<0, 2><<<dim3(8, 32), blk, 0, stream>>>(nullptr, nullptr, Am, nullptr,
                                                     WOb, nullptr, out, 4096, 1024, 1024);
}

// Round 3
// 707.753 us; speedup vs baseline: 3.0884x; 1.5853x over previous
//
#include <hip/hip_runtime.h>
#include <hip/hip_bf16.h>
#include <cstdint>
#include <cstddef>

// B=2, S=2048, D=1024, R=64, H=16, DH=64, N=32; BS=4096
typedef unsigned short u16;
typedef short bfrag __attribute__((ext_vector_type(8)));     // 8 bf16 = 4 VGPRs
typedef float f32x4 __attribute__((ext_vector_type(4)));
typedef u16 u16x8 __attribute__((ext_vector_type(8)));

__device__ __forceinline__ u16 f2bf(float v) {
    union { float f; unsigned u; } a; a.f = v;
    unsigned r = a.u + 0x7fff + ((a.u >> 16) & 1);   // RNE
    return (u16)(r >> 16);
}
__device__ __forceinline__ float bf2f(u16 u) {
    union { unsigned u; float f; } a; a.u = ((unsigned)u) << 16;
    return a.f;
}
__device__ __forceinline__ f32x4 mfma_bf16(bfrag a, bfrag b, f32x4 c) {
    return __builtin_amdgcn_mfma_f32_16x16x32_bf16(a, b, c, 0, 0, 0);
}
__device__ __forceinline__ void async_copy16(const void* g, void* l) {
    __builtin_amdgcn_global_load_lds(
        (const __attribute__((address_space(1))) unsigned*)g,
        (__attribute__((address_space(3))) unsigned*)l, 16, 0, 0);
}

// ---------------------------------------------------------------------------
// elementwise cast fp32 -> bf16 hi (+lo if SPLIT); n4 = count/4
// ---------------------------------------------------------------------------
template<int SPLIT>
__global__ __launch_bounds__(256) void cast_split(const float* __restrict__ s,
                                                  u16* __restrict__ dh,
                                                  u16* __restrict__ dl, int n4)
{
    int i = blockIdx.x * 256 + threadIdx.x;
    if (i >= n4) return;
    float4 v = ((const float4*)s)[i];
    float vv[4] = {v.x, v.y, v.z, v.w};
    ushort4 h, l;
    u16* hp = (u16*)&h; u16* lp = (u16*)&l;
#pragma unroll
    for (int e = 0; e < 4; ++e) {
        u16 hb = f2bf(vv[e]);
        hp[e] = hb;
        if (SPLIT) lp[e] = f2bf(vv[e] - bf2f(hb));
    }
    ((ushort4*)dh)[i] = h;
    if (SPLIT) ((ushort4*)dl)[i] = l;
}

// ---------------------------------------------------------------------------
// transpose + cast: dst[z*C + c][r] = src[z*R*C + r*C + c]; dst pitch = dpitch
// ---------------------------------------------------------------------------
template<int SPLIT>
__global__ __launch_bounds__(256) void transpose_cast(const float* __restrict__ src,
                                                      u16* __restrict__ dh,
                                                      u16* __restrict__ dl,
                                                      int R, int C, int dpitch)
{
    __shared__ float t[32][33];
    int z = blockIdx.z;
    const float* s = src + (size_t)z * R * C;
    int r0 = blockIdx.y * 32, c0 = blockIdx.x * 32;
    int tx = threadIdx.x & 31, ty = threadIdx.x >> 5;
#pragma unroll
    for (int p = 0; p < 4; ++p)
        t[ty + p * 8][tx] = s[(size_t)(r0 + ty + p * 8) * C + c0 + tx];
    __syncthreads();
#pragma unroll
    for (int p = 0; p < 4; ++p) {
        int rr = ty + p * 8;
        float v = t[tx][rr];
        size_t di = (size_t)(z * C + c0 + rr) * dpitch + r0 + tx;
        u16 hb = f2bf(v);
        dh[di] = hb;
        if (SPLIT) dl[di] = f2bf(v - bf2f(hb));
    }
}

// ---------------------------------------------------------------------------
// MFMA GEMM: C[M,N] = A[M,K] @ BT[N,K]^T, 128x128 tile, BK=32, 4 waves.
// LDS granule g (16B = 8 bf16) of row r stored at slot r*4 + (g ^ ((r>>1)&3)).
// SPLIT: hi/lo bf16 operands, 3 MFMAs (AhBh + AhBl + AlBh) ~ fp32 precision.
// AMODE 0: A from pre-cast bf16 arrays (global_load_lds)
// AMODE 1: A[i][k] = h[i][k&63] * w[i][k>>6], split on the fly (fp32 sources)
// EPI 0: fp32 C row-major. EPI 1: bf16 hi/lo to [bh][s][dh] arrays Ch/Cl.
// EPI 2: bf16 single to transposed [bh][dh][s] array Ch.
// ---------------------------------------------------------------------------
template<int SPLIT, int AMODE, int EPI>
__global__ __launch_bounds__(256) void gemm_mfma(const u16* __restrict__ Agh,
                                                 const u16* __restrict__ Agl,
                                                 const float* __restrict__ hA,
                                                 const float* __restrict__ wA,
                                                 const u16* __restrict__ Bgh,
                                                 const u16* __restrict__ Bgl,
                                                 float* __restrict__ C,
                                                 u16* __restrict__ Ch,
                                                 u16* __restrict__ Cl,
                                                 int M, int N, int K)
{
    constexpr int NBUF = SPLIT ? 4 : 2;
    __shared__ u16 lds[NBUF * 4096];
    u16* Ath = lds;
    u16* Atl = SPLIT ? (lds + 4096) : lds;
    u16* Bth = lds + (SPLIT ? 8192 : 4096);
    u16* Btl = SPLIT ? (lds + 12288) : lds;

    const int tid  = threadIdx.x;
    const int lane = tid & 63;
    const int wv   = tid >> 6;
    const int q    = lane >> 4;
    const int tn   = lane & 15;
    const int wm   = (wv >> 1) * 64;
    const int wn   = (wv & 1) * 64;
    const int row0 = blockIdx.y * 128;
    const int col0 = blockIdx.x * 128;
    const int wbase = (tid & 192) * 8;   // wave-uniform LDS offset (u16 units)

    f32x4 acc[4][4];
#pragma unroll
    for (int i = 0; i < 4; ++i)
#pragma unroll
        for (int j = 0; j < 4; ++j) acc[i][j] = 0.f;

    for (int k0 = 0; k0 < K; k0 += 32) {
        // ---- stage B (always async) ----
#pragma unroll
        for (int shot = 0; shot < 2; ++shot) {
            int G = tid + shot * 256;
            int row = G >> 2, kgs = G & 3;
            int kgg = kgs ^ ((row >> 1) & 3);
            size_t goff = (size_t)(col0 + row) * K + k0 + kgg * 8;
            async_copy16(Bgh + goff, Bth + shot * 2048 + wbase);
            if (SPLIT) async_copy16(Bgl + goff, Btl + shot * 2048 + wbase);
        }
        // ---- stage A ----
        if (AMODE == 0) {
#pragma unroll
            for (int shot = 0; shot < 2; ++shot) {
                int G = tid + shot * 256;
                int row = G >> 2, kgs = G & 3;
                int kgg = kgs ^ ((row >> 1) & 3);
                size_t goff = (size_t)(row0 + row) * K + k0 + kgg * 8;
                async_copy16(Agh + goff, Ath + shot * 2048 + wbase);
                if (SPLIT) async_copy16(Agl + goff, Atl + shot * 2048 + wbase);
            }
        } else {
            const int r = tid >> 1;
            float wmul = wA[(size_t)(row0 + r) * 32 + (k0 >> 6)];
#pragma unroll
            for (int gi = 0; gi < 2; ++gi) {
                int gg = (tid & 1) * 2 + gi;
                const float* sp = hA + (size_t)(row0 + r) * 64 + (k0 & 63) + gg * 8;
                float4 v0 = *(const float4*)sp;
                float4 v1 = *(const float4*)(sp + 4);
                float vv[8] = {v0.x, v0.y, v0.z, v0.w, v1.x, v1.y, v1.z, v1.w};
                u16x8 hi, lo;
#pragma unroll
                for (int e = 0; e < 8; ++e) {
                    float val = vv[e] * wmul;
                    u16 hb = f2bf(val);
                    hi[e] = hb;
                    if (SPLIT) lo[e] = f2bf(val - bf2f(hb));
                }
                int slot = r * 4 + (gg ^ ((r >> 1) & 3));
                *(u16x8*)(Ath + slot * 8) = hi;
                if (SPLIT) *(u16x8*)(Atl + slot * 8) = lo;
            }
        }
        __syncthreads();

        bfrag ah[4], bh[4], al[4], bl[4];
#pragma unroll
        for (int i = 0; i < 4; ++i) {
            int m = wm + i * 16 + tn;
            int g = m * 4 + (q ^ ((m >> 1) & 3));
            ah[i] = *(const bfrag*)(Ath + g * 8);
            if (SPLIT) al[i] = *(const bfrag*)(Atl + g * 8);
        }
#pragma unroll
        for (int j = 0; j < 4; ++j) {
            int n = wn + j * 16 + tn;
            int g = n * 4 + (q ^ ((n >> 1) & 3));
            bh[j] = *(const bfrag*)(Bth + g * 8);
            if (SPLIT) bl[j] = *(const bfrag*)(Btl + g * 8);
        }
#pragma unroll
        for (int i = 0; i < 4; ++i)
#pragma unroll
            for (int j = 0; j < 4; ++j) {
                acc[i][j] = mfma_bf16(ah[i], bh[j], acc[i][j]);
                if (SPLIT) {
                    acc[i][j] = mfma_bf16(ah[i], bl[j], acc[i][j]);
                    acc[i][j] = mfma_bf16(al[i], bh[j], acc[i][j]);
                }
            }
        __syncthreads();
    }

    // epilogue: C/D layout col=lane&15, row=(lane>>4)*4+reg  [m89-verified]
#pragma unroll
    for (int i = 0; i < 4; ++i)
#pragma unroll
        for (int j = 0; j < 4; ++j)
#pragma unroll
            for (int rg = 0; rg < 4; ++rg) {
                int row = row0 + wm + i * 16 + q * 4 + rg;
                int col = col0 + wn + j * 16 + tn;
                float v = acc[i][j][rg];
                if (EPI == 0) {
                    C[(size_t)row * N + col] = v;
                } else if (EPI == 1) {
                    size_t idx = (((size_t)(row >> 11) * 16 + (col >> 6)) << 17)
                               | ((size_t)(row & 2047) << 6) | (size_t)(col & 63);
                    u16 hb = f2bf(v);
                    Ch[idx] = hb;
                    Cl[idx] = f2bf(v - bf2f(hb));
                } else {
                    size_t idx = ((((size_t)(row >> 11) * 16 + (col >> 6)) * 64
                                  + (size_t)(col & 63)) << 11) | (size_t)(row & 2047);
                    Ch[idx] = f2bf(v);
                }
            }
}

// ---------------------------------------------------------------------------
// Mix: h1[bs,r] = sum_n w1[bs,n] * P[bs, n*64+r]  (optionally h2 with w2)
// ---------------------------------------------------------------------------
__global__ __launch_bounds__(256) void mix_kernel(const float* __restrict__ P,
                                                  const float* __restrict__ w1,
                                                  const float* __restrict__ w2,
                                                  float* __restrict__ h1,
                                                  float* __restrict__ h2,
                                                  int two)
{
    int tid = blockIdx.x * 256 + threadIdx.x;
    int bs = tid >> 6;
    int r  = tid & 63;
    const float* Pp = P + (size_t)bs * 2048 + r;
    float a = 0.f, b = 0.f;
#pragma unroll
    for (int n = 0; n < 32; ++n) {
        float p = Pp[n * 64];
        a = fmaf(w1[bs * 32 + n], p, a);
        if (two) b = fmaf(w2[bs * 32 + n], p, b);
    }
    h1[tid] = a;
    if (two) h2[tid] = b;
}

// ---------------------------------------------------------------------------
// MFMA causal flash attention. Block = 64 queries x 4 waves (16 q-rows/wave),
// K-tile 64. Tiles in LDS pitch-64 bf16 with granule XOR swizzle
// (slot = g ^ (row&7)) -> all ds_read_b128 frag loads are 2-way (free, m136)
// and global_load_lds staging stays lane-contiguous (m104-safe).
// Scores split-precision: Qh*Kh + Qh*Kl + Ql*Kh (~fp32). P via LDS round-trip
// (C-layout -> A-layout, m120 pattern). Output written bf16 [bs][d].
// ---------------------------------------------------------------------------
__device__ __forceinline__ void stage_tile(u16* dst, const u16* src, int rowstride,
                                           int tid, int wuni)
{
#pragma unroll
    for (int shot = 0; shot < 2; ++shot) {
        int sl = shot * 256 + tid;
        int m = sl >> 3, s = sl & 7, g = s ^ (m & 7);
        async_copy16(src + (size_t)m * rowstride + g * 8, dst + shot * 2048 + wuni);
    }
}

__global__ __launch_bounds__(256) void flash_mfma(const u16* __restrict__ Qh_g,
                                                  const u16* __restrict__ Ql_g,
                                                  const u16* __restrict__ Kh_g,
                                                  const u16* __restrict__ Kl_g,
                                                  const u16* __restrict__ Vt_g,
                                                  u16* __restrict__ Oo)
{
    const int bh = blockIdx.y;
    const int qb = 31 - (int)blockIdx.x;    // heavy tiles launch first
    const int q0 = qb * 64;
    const int tid = threadIdx.x;
    const int lane = tid & 63;
    const int wv = tid >> 6;
    const int q = lane >> 4;
    const int tn = lane & 15;
    const int wuni = (tid & 192) * 8;

    __shared__ u16 sQh[4096], sQl[4096], sKh[4096], sKl[4096], sVt[4096], sP[4096];

    const size_t qoff = ((size_t)bh * 2048 + q0) * 64;
    stage_tile(sQh, Qh_g + qoff, 64, tid, wuni);
    stage_tile(sQl, Ql_g + qoff, 64, tid, wuni);
    __syncthreads();

    bfrag qfh[2], qfl[2];
#pragma unroll
    for (int ks = 0; ks < 2; ++ks) {
        int m = wv * 16 + tn;
        int slot = (ks * 4 + q) ^ (m & 7);
        qfh[ks] = *(const bfrag*)(sQh + m * 64 + slot * 8);
        qfl[ks] = *(const bfrag*)(sQl + m * 64 + slot * 8);
    }

    float m_i[4], l_i[4];
    f32x4 acc_o[4];
#pragma unroll
    for (int rg = 0; rg < 4; ++rg) { m_i[rg] = -3.0e38f; l_i[rg] = 0.f; }
#pragma unroll
    for (int dt = 0; dt < 4; ++dt) acc_o[dt] = 0.f;

    const size_t kbase = (size_t)bh * 2048 * 64;
    const size_t vbase = (size_t)bh * 64 * 2048;

    for (int kt = 0; kt <= qb; ++kt) {
        const int k0 = kt * 64;
        __syncthreads();   // prior iter's LDS reads (incl. PV) complete
        stage_tile(sKh, Kh_g + kbase + (size_t)k0 * 64, 64, tid, wuni);
        stage_tile(sKl, Kl_g + kbase + (size_t)k0 * 64, 64, tid, wuni);
        stage_tile(sVt, Vt_g + vbase + k0, 2048, tid, wuni);
        __syncthreads();   // staging visible (syncthreads drains vmcnt)

        // ---- QK^T: S[16 q-rows][64 keys] per wave, split precision ----
        f32x4 accs[4];
#pragma unroll
        for (int n = 0; n < 4; ++n) accs[n] = 0.f;
#pragma unroll
        for (int n = 0; n < 4; ++n) {
#pragma unroll
            for (int ks = 0; ks < 2; ++ks) {
                int r = n * 16 + tn;
                int slot = (ks * 4 + q) ^ (r & 7);
                bfrag kh = *(const bfrag*)(sKh + r * 64 + slot * 8);
                bfrag kl = *(const bfrag*)(sKl + r * 64 + slot * 8);
                accs[n] = mfma_bf16(qfh[ks], kh, accs[n]);
                accs[n] = mfma_bf16(qfh[ks], kl, accs[n]);
                accs[n] = mfma_bf16(qfl[ks], kh, accs[n]);
            }
        }
        // ---- scale + causal mask (only diagonal tile needs masking) ----
        const bool diag = (kt == qb);
#pragma unroll
        for (int n = 0; n < 4; ++n)
#pragma unroll
            for (int rg = 0; rg < 4; ++rg) {
                float v = accs[n][rg] * 0.125f;
                if (diag && (n * 16 + tn > wv * 16 + q * 4 + rg)) v = -3.0e38f;
                accs[n][rg] = v;
            }
        // ---- online softmax: rows live across the 16 lanes of a quad ----
        float alpha[4], mnew[4], ssum[4];
#pragma unroll
        for (int rg = 0; rg < 4; ++rg) {
            float mx = fmaxf(fmaxf(accs[0][rg], accs[1][rg]),
                             fmaxf(accs[2][rg], accs[3][rg]));
#pragma unroll
            for (int xm = 1; xm < 16; xm <<= 1)
                mx = fmaxf(mx, __shfl_xor(mx, xm, 64));
            mnew[rg] = fmaxf(m_i[rg], mx);
            alpha[rg] = __expf(m_i[rg] - mnew[rg]);
            m_i[rg] = mnew[rg];
            ssum[rg] = 0.f;
        }
#pragma unroll
        for (int n = 0; n < 4; ++n)
#pragma unroll
            for (int rg = 0; rg < 4; ++rg) {
                float p = __expf(accs[n][rg] - mnew[rg]);
                ssum[rg] += p;
                int m = wv * 16 + q * 4 + rg;
                int c = n * 16 + tn;
                int slot = (c >> 3) ^ (m & 7);
                sP[m * 64 + slot * 8 + (c & 7)] = f2bf(p);
            }
#pragma unroll
        for (int rg = 0; rg < 4; ++rg) {
            float sm = ssum[rg];
#pragma unroll
            for (int xm = 1; xm < 16; xm <<= 1)
                sm += __shfl_xor(sm, xm, 64);
            l_i[rg] = l_i[rg] * alpha[rg] + sm;
#pragma unroll
            for (int dt = 0; dt < 4; ++dt) acc_o[dt][rg] *= alpha[rg];
        }
        // ---- PV: O += P @ V  (P rows are wave-local; in-wave LDS ordering) ----
#pragma unroll
        for (int ks = 0; ks < 2; ++ks) {
            int m = wv * 16 + tn;
            int slot = (ks * 4 + q) ^ (m & 7);
            bfrag pf = *(const bfrag*)(sP + m * 64 + slot * 8);
#pragma unroll
            for (int dt = 0; dt < 4; ++dt) {
                int d = dt * 16 + tn;
                int vslot = (ks * 4 + q) ^ (d & 7);
                bfrag vf = *(const bfrag*)(sVt + d * 64 + vslot * 8);
                acc_o[dt] = mfma_bf16(pf, vf, acc_o[dt]);
            }
        }
    }

    // ---- epilogue: O / l -> bf16 [bs][1024] ----
#pragma unroll
    for (int dt = 0; dt < 4; ++dt)
#pragma unroll
        for (int rg = 0; rg < 4; ++rg) {
            int srow = q0 + wv * 16 + q * 4 + rg;
            float v = acc_o[dt][rg] / l_i[rg];
            size_t idx = ((size_t)(bh >> 4) * 2048 + srow) * 1024
                       + (size_t)((bh & 15) * 64 + dt * 16 + tn);
            Oo[idx] = f2bf(v);
        }
}

// ---------------------------------------------------------------------------
extern "C" void kernel_launch(void* const* d_in, const int* in_sizes, int n_in,
                              void* d_out, int out_size, void* d_ws, size_t ws_size,
                              hipStream_t stream)
{
    const float* x     = (const float*)d_in[0];
    const float* wfqkQ = (const float*)d_in[1];
    const float* wfqkK = (const float*)d_in[2];
    const float* wfv   = (const float*)d_in[3];
    const float* wrqkQ = (const float*)d_in[4];
    const float* wrqkK = (const float*)d_in[5];
    const float* wrv   = (const float*)d_in[6];
    const float* f_qk  = (const float*)d_in[7];
    const float* f_v   = (const float*)d_in[8];
    const float* r_qk  = (const float*)d_in[9];
    const float* r_v   = (const float*)d_in[10];
    const float* W_O   = (const float*)d_in[11];
    float* out = (float*)d_out;

    const size_t MB = 1u << 20;
    char* w8 = (char*)d_ws;
    u16*  WOb   = (u16*)(w8 + 0);          //  2MB [1024][1024]
    u16*  FqkTh = (u16*)(w8 + 2  * MB);    //  4MB [2048][1024]
    u16*  FqkTl = (u16*)(w8 + 6  * MB);
    u16*  FvT   = (u16*)(w8 + 10 * MB);
    u16*  RqkTh = (u16*)(w8 + 14 * MB);    //  4MB [1024][2048]
    u16*  RqkTl = (u16*)(w8 + 18 * MB);
    u16*  RvT   = (u16*)(w8 + 22 * MB);
    float* h_q  = (float*)(w8 + 26 * MB);  //  1MB each
    float* h_k  = (float*)(w8 + 27 * MB);
    float* h_v  = (float*)(w8 + 28 * MB);
    u16*  x_hi  = (u16*)(w8 + 30 * MB);    //  8MB
    u16*  x_lo  = (u16*)(w8 + 38 * MB);
    float* P    = (float*)(w8 + 48 * MB);  // 32MB fp32 (dead after mix)
    u16*  Qh    = (u16*)(w8 + 48 * MB);    //  8MB each, [bh][s][dh] (over P)
    u16*  Ql    = (u16*)(w8 + 56 * MB);
    u16*  Kh    = (u16*)(w8 + 64 * MB);
    u16*  Kl    = (u16*)(w8 + 72 * MB);
    u16*  Vt    = (u16*)(w8 + 80 * MB);    //  8MB [bh][dh][s]
    u16*  Am    = (u16*)(w8 + 88 * MB);    //  8MB bf16 attn out -> 96MB total

    dim3 blk(256);

    // casts / transposes
    cast_split<1><<<dim3(4096), blk, 0, stream>>>(x, x_hi, x_lo, 1024 * 1024);
    cast_split<0><<<dim3(1024), blk, 0, stream>>>(W_O, WOb, nullptr, 256 * 1024);
    transpose_cast<1><<<dim3(2, 32, 32), blk, 0, stream>>>(f_qk, FqkTh, FqkTl, 1024, 64, 1024);
    transpose_cast<0><<<dim3(2, 32, 32), blk, 0, stream>>>(f_v,  FvT,   nullptr, 1024, 64, 1024);
    transpose_cast<1><<<dim3(32, 64, 1), blk, 0, stream>>>(r_qk, RqkTh, RqkTl, 2048, 1024, 2048);
    transpose_cast<0><<<dim3(32, 64, 1), blk, 0, stream>>>(r_v,  RvT,   nullptr, 2048, 1024, 2048);

    // project + mix
    gemm_mfma<1, 0, 0><<<dim3(16, 32), blk, 0, stream>>>(x_hi, x_lo, nullptr, nullptr,
        FqkTh, FqkTl, P, nullptr, nullptr, 4096, 2048, 1024);
    mix_kernel<<<dim3(1024), blk, 0, stream>>>(P, wfqkQ, wfqkK, h_q, h_k, 1);
    gemm_mfma<0, 0, 0><<<dim3(16, 32), blk, 0, stream>>>(x_hi, nullptr, nullptr, nullptr,
        FvT, nullptr, P, nullptr, nullptr, 4096, 2048, 1024);
    mix_kernel<<<dim3(1024), blk, 0, stream>>>(P, wfv, nullptr, h_v, nullptr, 0);

    // restore -> bf16 attention operands (Q,K split hi/lo; V single, transposed)
    gemm_mfma<1, 1, 1><<<dim3(8, 32), blk, 0, stream>>>(nullptr, nullptr, h_q, wrqkQ,
        RqkTh, RqkTl, nullptr, Qh, Ql, 4096, 1024, 2048);
    gemm_mfma<1, 1, 1><<<dim3(8, 32), blk, 0, stream>>>(nullptr, nullptr, h_k, wrqkK,
        RqkTh, RqkTl, nullptr, Kh, Kl, 4096, 1024, 2048);
    gemm_mfma<0, 1, 2><<<dim3(8, 32), blk, 0, stream>>>(nullptr, nullptr, h_v, wrv,
        RvT, nullptr, nullptr, Vt, nullptr, 4096, 1024, 2048);

    // MFMA flash attention + output projection
    flash_mfma<<<dim3(32, 32), blk, 0, stream>>>(Qh, Ql, Kh, Kl, Vt, Am);
    gemm_mfma<0, 0, 0><<<dim3(8, 32), blk, 0, stream>>>(Am, nullptr, nullptr, nullptr,
        WOb, nullptr, out, nullptr, nullptr, 4096, 1024, 1024);
}

// Round 4
// 655.725 us; speedup vs baseline: 3.3335x; 1.0793x over previous
//
#include <hip/hip_runtime.h>
#include <hip/hip_bf16.h>
#include <cstdint>
#include <cstddef>

// B=2, S=2048, D=1024, R=64, H=16, DH=64, N=32; BS=4096
typedef unsigned short u16;
typedef short bfrag __attribute__((ext_vector_type(8)));     // 8 bf16 = 4 VGPRs
typedef float f32x4 __attribute__((ext_vector_type(4)));
typedef u16 u16x8 __attribute__((ext_vector_type(8)));

__device__ __forceinline__ u16 f2bf(float v) {
    union { float f; unsigned u; } a; a.f = v;
    unsigned r = a.u + 0x7fff + ((a.u >> 16) & 1);   // RNE
    return (u16)(r >> 16);
}
__device__ __forceinline__ float bf2f(u16 u) {
    union { unsigned u; float f; } a; a.u = ((unsigned)u) << 16;
    return a.f;
}
__device__ __forceinline__ f32x4 mfma_bf16(bfrag a, bfrag b, f32x4 c) {
    return __builtin_amdgcn_mfma_f32_16x16x32_bf16(a, b, c, 0, 0, 0);
}
__device__ __forceinline__ void async_copy16(const void* g, void* l) {
    __builtin_amdgcn_global_load_lds(
        (const __attribute__((address_space(1))) unsigned*)g,
        (__attribute__((address_space(3))) unsigned*)l, 16, 0, 0);
}

// ---------------------------------------------------------------------------
// elementwise cast fp32 -> bf16 hi (+lo if SPLIT); n4 = count/4
// ---------------------------------------------------------------------------
template<int SPLIT>
__global__ __launch_bounds__(256) void cast_split(const float* __restrict__ s,
                                                  u16* __restrict__ dh,
                                                  u16* __restrict__ dl, int n4)
{
    int i = blockIdx.x * 256 + threadIdx.x;
    if (i >= n4) return;
    float4 v = ((const float4*)s)[i];
    float vv[4] = {v.x, v.y, v.z, v.w};
    ushort4 h, l;
    u16* hp = (u16*)&h; u16* lp = (u16*)&l;
#pragma unroll
    for (int e = 0; e < 4; ++e) {
        u16 hb = f2bf(vv[e]);
        hp[e] = hb;
        if (SPLIT) lp[e] = f2bf(vv[e] - bf2f(hb));
    }
    ((ushort4*)dh)[i] = h;
    if (SPLIT) ((ushort4*)dl)[i] = l;
}

// ---------------------------------------------------------------------------
// transpose + cast: dst[z*C + c][r] = src[z*R*C + r*C + c]; dst pitch = dpitch
// ---------------------------------------------------------------------------
template<int SPLIT>
__global__ __launch_bounds__(256) void transpose_cast(const float* __restrict__ src,
                                                      u16* __restrict__ dh,
                                                      u16* __restrict__ dl,
                                                      int R, int C, int dpitch)
{
    __shared__ float t[32][33];
    int z = blockIdx.z;
    const float* s = src + (size_t)z * R * C;
    int r0 = blockIdx.y * 32, c0 = blockIdx.x * 32;
    int tx = threadIdx.x & 31, ty = threadIdx.x >> 5;
#pragma unroll
    for (int p = 0; p < 4; ++p)
        t[ty + p * 8][tx] = s[(size_t)(r0 + ty + p * 8) * C + c0 + tx];
    __syncthreads();
#pragma unroll
    for (int p = 0; p < 4; ++p) {
        int rr = ty + p * 8;
        float v = t[tx][rr];
        size_t di = (size_t)(z * C + c0 + rr) * dpitch + r0 + tx;
        u16 hb = f2bf(v);
        dh[di] = hb;
        if (SPLIT) dl[di] = f2bf(v - bf2f(hb));
    }
}

// ---------------------------------------------------------------------------
// MFMA GEMM (project / outproj): C[M,N] = A[M,K] @ BT[N,K]^T, 128x128, BK=32.
// A,B pre-cast bf16, global_load_lds staging. SPLIT: 3-MFMA hi/lo (~fp32).
// ---------------------------------------------------------------------------
template<int SPLIT>
__global__ __launch_bounds__(256) void gemm_mfma(const u16* __restrict__ Agh,
                                                 const u16* __restrict__ Agl,
                                                 const u16* __restrict__ Bgh,
                                                 const u16* __restrict__ Bgl,
                                                 float* __restrict__ C,
                                                 int M, int N, int K)
{
    constexpr int NBUF = SPLIT ? 4 : 2;
    __shared__ u16 lds[NBUF * 4096];
    u16* Ath = lds;
    u16* Atl = SPLIT ? (lds + 4096) : lds;
    u16* Bth = lds + (SPLIT ? 8192 : 4096);
    u16* Btl = SPLIT ? (lds + 12288) : lds;

    const int tid  = threadIdx.x;
    const int lane = tid & 63;
    const int wv   = tid >> 6;
    const int q    = lane >> 4;
    const int tn   = lane & 15;
    const int wm   = (wv >> 1) * 64;
    const int wn   = (wv & 1) * 64;
    const int row0 = blockIdx.y * 128;
    const int col0 = blockIdx.x * 128;
    const int wbase = (tid & 192) * 8;

    f32x4 acc[4][4];
#pragma unroll
    for (int i = 0; i < 4; ++i)
#pragma unroll
        for (int j = 0; j < 4; ++j) acc[i][j] = 0.f;

    for (int k0 = 0; k0 < K; k0 += 32) {
#pragma unroll
        for (int shot = 0; shot < 2; ++shot) {
            int G = tid + shot * 256;
            int row = G >> 2, kgs = G & 3;
            int kgg = kgs ^ ((row >> 1) & 3);
            size_t goffB = (size_t)(col0 + row) * K + k0 + kgg * 8;
            async_copy16(Bgh + goffB, Bth + shot * 2048 + wbase);
            if (SPLIT) async_copy16(Bgl + goffB, Btl + shot * 2048 + wbase);
            size_t goffA = (size_t)(row0 + row) * K + k0 + kgg * 8;
            async_copy16(Agh + goffA, Ath + shot * 2048 + wbase);
            if (SPLIT) async_copy16(Agl + goffA, Atl + shot * 2048 + wbase);
        }
        __syncthreads();

        bfrag ah[4], bh[4], al[4], bl[4];
#pragma unroll
        for (int i = 0; i < 4; ++i) {
            int m = wm + i * 16 + tn;
            int g = m * 4 + (q ^ ((m >> 1) & 3));
            ah[i] = *(const bfrag*)(Ath + g * 8);
            if (SPLIT) al[i] = *(const bfrag*)(Atl + g * 8);
        }
#pragma unroll
        for (int j = 0; j < 4; ++j) {
            int n = wn + j * 16 + tn;
            int g = n * 4 + (q ^ ((n >> 1) & 3));
            bh[j] = *(const bfrag*)(Bth + g * 8);
            if (SPLIT) bl[j] = *(const bfrag*)(Btl + g * 8);
        }
#pragma unroll
        for (int i = 0; i < 4; ++i)
#pragma unroll
            for (int j = 0; j < 4; ++j) {
                acc[i][j] = mfma_bf16(ah[i], bh[j], acc[i][j]);
                if (SPLIT) {
                    acc[i][j] = mfma_bf16(ah[i], bl[j], acc[i][j]);
                    acc[i][j] = mfma_bf16(al[i], bh[j], acc[i][j]);
                }
            }
        __syncthreads();
    }

#pragma unroll
    for (int i = 0; i < 4; ++i)
#pragma unroll
        for (int j = 0; j < 4; ++j)
#pragma unroll
            for (int rg = 0; rg < 4; ++rg) {
                int row = row0 + wm + i * 16 + q * 4 + rg;
                int col = col0 + wn + j * 16 + tn;
                C[(size_t)row * N + col] = acc[i][j][rg];
            }
}

// ---------------------------------------------------------------------------
// Fused restore GEMMs: one launch, grid (24, 32); bx>>3 selects Q/K/V.
// Q,K: split-precision (3 MFMA), epilogue -> bf16 hi/lo [bh][s][dh].
// V: single bf16, epilogue -> transposed [bh][dh][s].
// A[i][k] = h[i][k&63] * w[i][k>>6] built on the fly (fp32 sources).
// ---------------------------------------------------------------------------
__global__ __launch_bounds__(256) void restore_mega(
    const float* __restrict__ h_q, const float* __restrict__ wQ,
    const float* __restrict__ h_k, const float* __restrict__ wK,
    const float* __restrict__ h_v, const float* __restrict__ wV,
    const u16* __restrict__ Rqh, const u16* __restrict__ Rql,
    const u16* __restrict__ Rvh,
    u16* __restrict__ Qh, u16* __restrict__ Ql,
    u16* __restrict__ Kh, u16* __restrict__ Kl,
    u16* __restrict__ Vt)
{
    const int sel = blockIdx.x >> 3;          // 0=Q, 1=K, 2=V
    const bool split = (sel < 2);
    const float* hA = (sel == 0) ? h_q : (sel == 1) ? h_k : h_v;
    const float* wA = (sel == 0) ? wQ  : (sel == 1) ? wK  : wV;
    const u16* Bgh = split ? Rqh : Rvh;
    const u16* Bgl = Rql;
    u16* Ch = (sel == 0) ? Qh : (sel == 1) ? Kh : Vt;
    u16* Cl = (sel == 0) ? Ql : Kl;
    const int N = 1024, K = 2048;

    __shared__ u16 lds[16384];
    u16* Ath = lds;
    u16* Atl = lds + 4096;
    u16* Bth = lds + 8192;
    u16* Btl = lds + 12288;

    const int tid  = threadIdx.x;
    const int lane = tid & 63;
    const int wv   = tid >> 6;
    const int q    = lane >> 4;
    const int tn   = lane & 15;
    const int wm   = (wv >> 1) * 64;
    const int wn   = (wv & 1) * 64;
    const int row0 = blockIdx.y * 128;
    const int col0 = (blockIdx.x & 7) * 128;
    const int wbase = (tid & 192) * 8;

    f32x4 acc[4][4];
#pragma unroll
    for (int i = 0; i < 4; ++i)
#pragma unroll
        for (int j = 0; j < 4; ++j) acc[i][j] = 0.f;

    for (int k0 = 0; k0 < K; k0 += 32) {
        // B staging (async)
#pragma unroll
        for (int shot = 0; shot < 2; ++shot) {
            int G = tid + shot * 256;
            int row = G >> 2, kgs = G & 3;
            int kgg = kgs ^ ((row >> 1) & 3);
            size_t goff = (size_t)(col0 + row) * K + k0 + kgg * 8;
            async_copy16(Bgh + goff, Bth + shot * 2048 + wbase);
            if (split) async_copy16(Bgl + goff, Btl + shot * 2048 + wbase);
        }
        // A on the fly: hw product, split into hi/lo
        {
            const int r = tid >> 1;
            float wmul = wA[(size_t)(row0 + r) * 32 + (k0 >> 6)];
#pragma unroll
            for (int gi = 0; gi < 2; ++gi) {
                int gg = (tid & 1) * 2 + gi;
                const float* sp = hA + (size_t)(row0 + r) * 64 + (k0 & 63) + gg * 8;
                float4 v0 = *(const float4*)sp;
                float4 v1 = *(const float4*)(sp + 4);
                float vv[8] = {v0.x, v0.y, v0.z, v0.w, v1.x, v1.y, v1.z, v1.w};
                u16x8 hi, lo;
#pragma unroll
                for (int e = 0; e < 8; ++e) {
                    float val = vv[e] * wmul;
                    u16 hb = f2bf(val);
                    hi[e] = hb;
                    lo[e] = f2bf(val - bf2f(hb));
                }
                int slot = r * 4 + (gg ^ ((r >> 1) & 3));
                *(u16x8*)(Ath + slot * 8) = hi;
                if (split) *(u16x8*)(Atl + slot * 8) = lo;
            }
        }
        __syncthreads();

        bfrag ah[4], bh[4], al[4], bl[4];
#pragma unroll
        for (int i = 0; i < 4; ++i) {
            int m = wm + i * 16 + tn;
            int g = m * 4 + (q ^ ((m >> 1) & 3));
            ah[i] = *(const bfrag*)(Ath + g * 8);
            if (split) al[i] = *(const bfrag*)(Atl + g * 8);
        }
#pragma unroll
        for (int j = 0; j < 4; ++j) {
            int n = wn + j * 16 + tn;
            int g = n * 4 + (q ^ ((n >> 1) & 3));
            bh[j] = *(const bfrag*)(Bth + g * 8);
            if (split) bl[j] = *(const bfrag*)(Btl + g * 8);
        }
#pragma unroll
        for (int i = 0; i < 4; ++i)
#pragma unroll
            for (int j = 0; j < 4; ++j) {
                acc[i][j] = mfma_bf16(ah[i], bh[j], acc[i][j]);
                if (split) {
                    acc[i][j] = mfma_bf16(ah[i], bl[j], acc[i][j]);
                    acc[i][j] = mfma_bf16(al[i], bh[j], acc[i][j]);
                }
            }
        __syncthreads();
    }

#pragma unroll
    for (int i = 0; i < 4; ++i)
#pragma unroll
        for (int j = 0; j < 4; ++j)
#pragma unroll
            for (int rg = 0; rg < 4; ++rg) {
                int row = row0 + wm + i * 16 + q * 4 + rg;
                int col = col0 + wn + j * 16 + tn;
                float v = acc[i][j][rg];
                if (sel < 2) {
                    size_t idx = (((size_t)(row >> 11) * 16 + (col >> 6)) << 17)
                               | ((size_t)(row & 2047) << 6) | (size_t)(col & 63);
                    u16 hb = f2bf(v);
                    Ch[idx] = hb;
                    Cl[idx] = f2bf(v - bf2f(hb));
                } else {
                    size_t idx = ((((size_t)(row >> 11) * 16 + (col >> 6)) * 64
                                  + (size_t)(col & 63)) << 11) | (size_t)(row & 2047);
                    Ch[idx] = f2bf(v);
                }
            }
}

// ---------------------------------------------------------------------------
// Mix: h1[bs,r] = sum_n w1[bs,n] * P[bs, n*64+r]  (optionally h2 with w2)
// ---------------------------------------------------------------------------
__global__ __launch_bounds__(256) void mix_kernel(const float* __restrict__ P,
                                                  const float* __restrict__ w1,
                                                  const float* __restrict__ w2,
                                                  float* __restrict__ h1,
                                                  float* __restrict__ h2,
                                                  int two)
{
    int tid = blockIdx.x * 256 + threadIdx.x;
    int bs = tid >> 6;
    int r  = tid & 63;
    const float* Pp = P + (size_t)bs * 2048 + r;
    float a = 0.f, b = 0.f;
#pragma unroll
    for (int n = 0; n < 32; ++n) {
        float p = Pp[n * 64];
        a = fmaf(w1[bs * 32 + n], p, a);
        if (two) b = fmaf(w2[bs * 32 + n], p, b);
    }
    h1[tid] = a;
    if (two) h2[tid] = b;
}

// ---------------------------------------------------------------------------
// MFMA causal flash attention. Q-tile=128 (4 waves x 32 q-rows), K-tile=64.
// LDS 56KB: sP aliases the K region (3 barriers/tile). Swizzle slot=g^(row&7):
// conflict-free ds_read_b128 + lane-contiguous global_load_lds.
// Scores split-precision (Qh*Kh + Qh*Kl + Ql*Kh). Fully-masked waves skip.
// ---------------------------------------------------------------------------
template<int SHOTS>
__device__ __forceinline__ void stage_tile(u16* dst, const u16* src, int rowstride,
                                           int tid, int wuni)
{
#pragma unroll
    for (int shot = 0; shot < SHOTS; ++shot) {
        int sl = shot * 256 + tid;
        int m = sl >> 3, s = sl & 7, g = s ^ (m & 7);
        async_copy16(src + (size_t)m * rowstride + g * 8, dst + shot * 2048 + wuni);
    }
}

__global__ __launch_bounds__(256) void flash_mfma(const u16* __restrict__ Qh_g,
                                                  const u16* __restrict__ Ql_g,
                                                  const u16* __restrict__ Kh_g,
                                                  const u16* __restrict__ Kl_g,
                                                  const u16* __restrict__ Vt_g,
                                                  u16* __restrict__ Oo)
{
    const int bh = blockIdx.y;
    const int qb = 15 - (int)blockIdx.x;    // heavy tiles launch first
    const int q0 = qb * 128;
    const int tid = threadIdx.x;
    const int lane = tid & 63;
    const int wv = tid >> 6;
    const int q = lane >> 4;
    const int tn = lane & 15;
    const int wuni = (tid & 192) * 8;

    __shared__ u16 smem[28672];             // 56 KB
    u16* sQh = smem;                        // 128x64
    u16* sQl = smem + 8192;                 // 128x64
    u16* sKh = smem + 16384;                // 64x64
    u16* sKl = smem + 20480;                // 64x64
    u16* sP  = smem + 16384;                // 128x64, aliases sKh/sKl
    u16* sVt = smem + 24576;                // 64x64

    const size_t qoff = ((size_t)bh * 2048 + q0) * 64;
    stage_tile<4>(sQh, Qh_g + qoff, 64, tid, wuni);
    stage_tile<4>(sQl, Ql_g + qoff, 64, tid, wuni);
    __syncthreads();

    bfrag qfh[2][2], qfl[2][2];
#pragma unroll
    for (int rg = 0; rg < 2; ++rg)
#pragma unroll
        for (int ks = 0; ks < 2; ++ks) {
            int m = wv * 32 + rg * 16 + tn;
            int slot = (ks * 4 + q) ^ (m & 7);
            qfh[rg][ks] = *(const bfrag*)(sQh + m * 64 + slot * 8);
            qfl[rg][ks] = *(const bfrag*)(sQl + m * 64 + slot * 8);
        }

    float m_i[2][4], l_i[2][4];
    f32x4 acc_o[2][4];
#pragma unroll
    for (int rg = 0; rg < 2; ++rg)
#pragma unroll
        for (int ri = 0; ri < 4; ++ri) { m_i[rg][ri] = -3.0e38f; l_i[rg][ri] = 0.f; }
#pragma unroll
    for (int rg = 0; rg < 2; ++rg)
#pragma unroll
        for (int dt = 0; dt < 4; ++dt) acc_o[rg][dt] = 0.f;

    const size_t kbase = (size_t)bh * 2048 * 64;
    const size_t vbase = (size_t)bh * 64 * 2048;
    const int nkt = 2 * qb + 2;

    for (int kt = 0; kt < nkt; ++kt) {
        const int k0 = kt * 64;
        __syncthreads();   // prior iter's sP/sK/sV reads complete
        stage_tile<2>(sKh, Kh_g + kbase + (size_t)k0 * 64, 64, tid, wuni);
        stage_tile<2>(sKl, Kl_g + kbase + (size_t)k0 * 64, 64, tid, wuni);
        stage_tile<2>(sVt, Vt_g + vbase + k0, 2048, tid, wuni);
        __syncthreads();   // staging landed

        const bool fullskip = (k0 > q0 + wv * 32 + 31);   // wave-uniform
        const bool anyMask  = !fullskip && (k0 + 63 > q0 + wv * 32);
        f32x4 accs[2][4];

        if (!fullskip) {
#pragma unroll
            for (int rg = 0; rg < 2; ++rg)
#pragma unroll
                for (int n = 0; n < 4; ++n) accs[rg][n] = 0.f;
#pragma unroll
            for (int n = 0; n < 4; ++n) {
                int r = n * 16 + tn;
#pragma unroll
                for (int ks = 0; ks < 2; ++ks) {
                    int slot = (ks * 4 + q) ^ (r & 7);
                    bfrag kh = *(const bfrag*)(sKh + r * 64 + slot * 8);
                    bfrag kl = *(const bfrag*)(sKl + r * 64 + slot * 8);
#pragma unroll
                    for (int rg = 0; rg < 2; ++rg) {
                        accs[rg][n] = mfma_bf16(qfh[rg][ks], kh, accs[rg][n]);
                        accs[rg][n] = mfma_bf16(qfh[rg][ks], kl, accs[rg][n]);
                        accs[rg][n] = mfma_bf16(qfl[rg][ks], kh, accs[rg][n]);
                    }
                }
            }
        }
        __syncthreads();   // QK reads of sKh/sKl done; sP may be written now

        if (!fullskip) {
#pragma unroll
            for (int rg = 0; rg < 2; ++rg) {
                // scale + causal mask
#pragma unroll
                for (int n = 0; n < 4; ++n)
#pragma unroll
                    for (int ri = 0; ri < 4; ++ri) {
                        float v = accs[rg][n][ri] * 0.125f;
                        if (anyMask &&
                            (k0 + n * 16 + tn > q0 + wv * 32 + rg * 16 + q * 4 + ri))
                            v = -3.0e38f;
                        accs[rg][n][ri] = v;
                    }
                float mnew[4], alpha[4], ssum[4];
#pragma unroll
                for (int ri = 0; ri < 4; ++ri) {
                    float mx = fmaxf(fmaxf(accs[rg][0][ri], accs[rg][1][ri]),
                                     fmaxf(accs[rg][2][ri], accs[rg][3][ri]));
#pragma unroll
                    for (int xm = 1; xm < 16; xm <<= 1)
                        mx = fmaxf(mx, __shfl_xor(mx, xm, 64));
                    mnew[ri] = fmaxf(m_i[rg][ri], mx);
                    alpha[ri] = __expf(m_i[rg][ri] - mnew[ri]);
                    m_i[rg][ri] = mnew[ri];
                    ssum[ri] = 0.f;
                }
#pragma unroll
                for (int n = 0; n < 4; ++n)
#pragma unroll
                    for (int ri = 0; ri < 4; ++ri) {
                        float p = __expf(accs[rg][n][ri] - mnew[ri]);
                        ssum[ri] += p;
                        int m = wv * 32 + rg * 16 + q * 4 + ri;
                        int c = n * 16 + tn;
                        int slot = (c >> 3) ^ (m & 7);
                        sP[m * 64 + slot * 8 + (c & 7)] = f2bf(p);
                    }
#pragma unroll
                for (int ri = 0; ri < 4; ++ri) {
                    float sm = ssum[ri];
#pragma unroll
                    for (int xm = 1; xm < 16; xm <<= 1)
                        sm += __shfl_xor(sm, xm, 64);
                    l_i[rg][ri] = l_i[rg][ri] * alpha[ri] + sm;
#pragma unroll
                    for (int dt = 0; dt < 4; ++dt) acc_o[rg][dt][ri] *= alpha[ri];
                }
            }
            // PV (wave-local sP rows; in-wave LDS ordering)
            bfrag pf[2][2];
#pragma unroll
            for (int rg = 0; rg < 2; ++rg)
#pragma unroll
                for (int ks = 0; ks < 2; ++ks) {
                    int m = wv * 32 + rg * 16 + tn;
                    int slot = (ks * 4 + q) ^ (m & 7);
                    pf[rg][ks] = *(const bfrag*)(sP + m * 64 + slot * 8);
                }
#pragma unroll
            for (int ks = 0; ks < 2; ++ks)
#pragma unroll
                for (int dt = 0; dt < 4; ++dt) {
                    int d = dt * 16 + tn;
                    int vslot = (ks * 4 + q) ^ (d & 7);
                    bfrag vf = *(const bfrag*)(sVt + d * 64 + vslot * 8);
#pragma unroll
                    for (int rg = 0; rg < 2; ++rg)
                        acc_o[rg][dt] = mfma_bf16(pf[rg][ks], vf, acc_o[rg][dt]);
                }
        }
    }

    // epilogue: O / l -> bf16 [bs][1024]
#pragma unroll
    for (int rg = 0; rg < 2; ++rg)
#pragma unroll
        for (int dt = 0; dt < 4; ++dt)
#pragma unroll
            for (int ri = 0; ri < 4; ++ri) {
                int srow = q0 + wv * 32 + rg * 16 + q * 4 + ri;
                float v = acc_o[rg][dt][ri] / l_i[rg][ri];
                size_t idx = ((size_t)(bh >> 4) * 2048 + srow) * 1024
                           + (size_t)((bh & 15) * 64 + dt * 16 + tn);
                Oo[idx] = f2bf(v);
            }
}

// ---------------------------------------------------------------------------
extern "C" void kernel_launch(void* const* d_in, const int* in_sizes, int n_in,
                              void* d_out, int out_size, void* d_ws, size_t ws_size,
                              hipStream_t stream)
{
    const float* x     = (const float*)d_in[0];
    const float* wfqkQ = (const float*)d_in[1];
    const float* wfqkK = (const float*)d_in[2];
    const float* wfv   = (const float*)d_in[3];
    const float* wrqkQ = (const float*)d_in[4];
    const float* wrqkK = (const float*)d_in[5];
    const float* wrv   = (const float*)d_in[6];
    const float* f_qk  = (const float*)d_in[7];
    const float* f_v   = (const float*)d_in[8];
    const float* r_qk  = (const float*)d_in[9];
    const float* r_v   = (const float*)d_in[10];
    const float* W_O   = (const float*)d_in[11];
    float* out = (float*)d_out;

    const size_t MB = 1u << 20;
    char* w8 = (char*)d_ws;
    u16*  WOb   = (u16*)(w8 + 0);          //  2MB [1024][1024]
    u16*  FqkTh = (u16*)(w8 + 2  * MB);    //  4MB [2048][1024]
    u16*  FqkTl = (u16*)(w8 + 6  * MB);
    u16*  FvT   = (u16*)(w8 + 10 * MB);
    u16*  RqkTh = (u16*)(w8 + 14 * MB);    //  4MB [1024][2048]
    u16*  RqkTl = (u16*)(w8 + 18 * MB);
    u16*  RvT   = (u16*)(w8 + 22 * MB);
    float* h_q  = (float*)(w8 + 26 * MB);  //  1MB each
    float* h_k  = (float*)(w8 + 27 * MB);
    float* h_v  = (float*)(w8 + 28 * MB);
    u16*  x_hi  = (u16*)(w8 + 30 * MB);    //  8MB
    u16*  x_lo  = (u16*)(w8 + 38 * MB);
    float* P    = (float*)(w8 + 48 * MB);  // 32MB fp32 (dead after mix)
    u16*  Qh    = (u16*)(w8 + 48 * MB);    //  8MB each, [bh][s][dh] (over P)
    u16*  Ql    = (u16*)(w8 + 56 * MB);
    u16*  Kh    = (u16*)(w8 + 64 * MB);
    u16*  Kl    = (u16*)(w8 + 72 * MB);
    u16*  Vt    = (u16*)(w8 + 80 * MB);    //  8MB [bh][dh][s]
    u16*  Am    = (u16*)(w8 + 88 * MB);    //  8MB bf16 attn out -> 96MB total

    dim3 blk(256);

    // casts / transposes
    cast_split<1><<<dim3(4096), blk, 0, stream>>>(x, x_hi, x_lo, 1024 * 1024);
    cast_split<0><<<dim3(1024), blk, 0, stream>>>(W_O, WOb, nullptr, 256 * 1024);
    transpose_cast<1><<<dim3(2, 32, 32), blk, 0, stream>>>(f_qk, FqkTh, FqkTl, 1024, 64, 1024);
    transpose_cast<0><<<dim3(2, 32, 32), blk, 0, stream>>>(f_v,  FvT,   nullptr, 1024, 64, 1024);
    transpose_cast<1><<<dim3(32, 64, 1), blk, 0, stream>>>(r_qk, RqkTh, RqkTl, 2048, 1024, 2048);
    transpose_cast<0><<<dim3(32, 64, 1), blk, 0, stream>>>(r_v,  RvT,   nullptr, 2048, 1024, 2048);

    // project + mix
    gemm_mfma<1><<<dim3(16, 32), blk, 0, stream>>>(x_hi, x_lo, FqkTh, FqkTl, P,
                                                   4096, 2048, 1024);
    mix_kernel<<<dim3(1024), blk, 0, stream>>>(P, wfqkQ, wfqkK, h_q, h_k, 1);
    gemm_mfma<0><<<dim3(16, 32), blk, 0, stream>>>(x_hi, nullptr, FvT, nullptr, P,
                                                   4096, 2048, 1024);
    mix_kernel<<<dim3(1024), blk, 0, stream>>>(P, wfv, nullptr, h_v, nullptr, 0);

    // fused restore -> bf16 attention operands
    restore_mega<<<dim3(24, 32), blk, 0, stream>>>(h_q, wrqkQ, h_k, wrqkK, h_v, wrv,
                                                   RqkTh, RqkTl, RvT,
                                                   Qh, Ql, Kh, Kl, Vt);

    // MFMA flash attention + output projection
    flash_mfma<<<dim3(16, 32), blk, 0, stream>>>(Qh, Ql, Kh, Kl, Vt, Am);
    gemm_mfma<0><<<dim3(8, 32), blk, 0, stream>>>(Am, nullptr, WOb, nullptr, out,
                                                  4096, 1024, 1024);
}

// Round 5
// 599.354 us; speedup vs baseline: 3.6470x; 1.0941x over previous
//
#include <hip/hip_runtime.h>
#include <hip/hip_bf16.h>
#include <cstdint>
#include <cstddef>

// B=2, S=2048, D=1024, R=64, H=16, DH=64, N=32; BS=4096
typedef unsigned short u16;
typedef short bfrag __attribute__((ext_vector_type(8)));     // 8 bf16 = 4 VGPRs
typedef float f32x4 __attribute__((ext_vector_type(4)));
typedef u16 u16x8 __attribute__((ext_vector_type(8)));

__device__ __forceinline__ u16 f2bf(float v) {
    union { float f; unsigned u; } a; a.f = v;
    unsigned r = a.u + 0x7fff + ((a.u >> 16) & 1);   // RNE
    return (u16)(r >> 16);
}
__device__ __forceinline__ float bf2f(u16 u) {
    union { unsigned u; float f; } a; a.u = ((unsigned)u) << 16;
    return a.f;
}
__device__ __forceinline__ f32x4 mfma_bf16(bfrag a, bfrag b, f32x4 c) {
    return __builtin_amdgcn_mfma_f32_16x16x32_bf16(a, b, c, 0, 0, 0);
}
__device__ __forceinline__ void async_copy16(const void* g, void* l) {
    __builtin_amdgcn_global_load_lds(
        (const __attribute__((address_space(1))) unsigned*)g,
        (__attribute__((address_space(3))) unsigned*)l, 16, 0, 0);
}

// ---------------------------------------------------------------------------
// elementwise cast fp32 -> bf16 hi (+lo if SPLIT); n4 = count/4
// ---------------------------------------------------------------------------
template<int SPLIT>
__global__ __launch_bounds__(256) void cast_split(const float* __restrict__ s,
                                                  u16* __restrict__ dh,
                                                  u16* __restrict__ dl, int n4)
{
    int i = blockIdx.x * 256 + threadIdx.x;
    if (i >= n4) return;
    float4 v = ((const float4*)s)[i];
    float vv[4] = {v.x, v.y, v.z, v.w};
    ushort4 h, l;
    u16* hp = (u16*)&h; u16* lp = (u16*)&l;
#pragma unroll
    for (int e = 0; e < 4; ++e) {
        u16 hb = f2bf(vv[e]);
        hp[e] = hb;
        if (SPLIT) lp[e] = f2bf(vv[e] - bf2f(hb));
    }
    ((ushort4*)dh)[i] = h;
    if (SPLIT) ((ushort4*)dl)[i] = l;
}

// ---------------------------------------------------------------------------
// transpose + cast: dst[z*C + c][r] = src[z*R*C + r*C + c]; dst pitch = dpitch
// ---------------------------------------------------------------------------
template<int SPLIT>
__global__ __launch_bounds__(256) void transpose_cast(const float* __restrict__ src,
                                                      u16* __restrict__ dh,
                                                      u16* __restrict__ dl,
                                                      int R, int C, int dpitch)
{
    __shared__ float t[32][33];
    int z = blockIdx.z;
    const float* s = src + (size_t)z * R * C;
    int r0 = blockIdx.y * 32, c0 = blockIdx.x * 32;
    int tx = threadIdx.x & 31, ty = threadIdx.x >> 5;
#pragma unroll
    for (int p = 0; p < 4; ++p)
        t[ty + p * 8][tx] = s[(size_t)(r0 + ty + p * 8) * C + c0 + tx];
    __syncthreads();
#pragma unroll
    for (int p = 0; p < 4; ++p) {
        int rr = ty + p * 8;
        float v = t[tx][rr];
        size_t di = (size_t)(z * C + c0 + rr) * dpitch + r0 + tx;
        u16 hb = f2bf(v);
        dh[di] = hb;
        if (SPLIT) dl[di] = f2bf(v - bf2f(hb));
    }
}

// ---------------------------------------------------------------------------
// MFMA GEMM (project / outproj): C[M,N] = A[M,K] @ BT[N,K]^T, 128x128, BK=32.
// A,B pre-cast bf16, global_load_lds staging. SPLIT: 3-MFMA hi/lo (~fp32).
// ---------------------------------------------------------------------------
template<int SPLIT>
__global__ __launch_bounds__(256) void gemm_mfma(const u16* __restrict__ Agh,
                                                 const u16* __restrict__ Agl,
                                                 const u16* __restrict__ Bgh,
                                                 const u16* __restrict__ Bgl,
                                                 float* __restrict__ C,
                                                 int M, int N, int K)
{
    constexpr int NBUF = SPLIT ? 4 : 2;
    __shared__ u16 lds[NBUF * 4096];
    u16* Ath = lds;
    u16* Atl = SPLIT ? (lds + 4096) : lds;
    u16* Bth = lds + (SPLIT ? 8192 : 4096);
    u16* Btl = SPLIT ? (lds + 12288) : lds;

    const int tid  = threadIdx.x;
    const int lane = tid & 63;
    const int wv   = tid >> 6;
    const int q    = lane >> 4;
    const int tn   = lane & 15;
    const int wm   = (wv >> 1) * 64;
    const int wn   = (wv & 1) * 64;
    const int row0 = blockIdx.y * 128;
    const int col0 = blockIdx.x * 128;
    const int wbase = (tid & 192) * 8;

    f32x4 acc[4][4];
#pragma unroll
    for (int i = 0; i < 4; ++i)
#pragma unroll
        for (int j = 0; j < 4; ++j) acc[i][j] = 0.f;

    for (int k0 = 0; k0 < K; k0 += 32) {
#pragma unroll
        for (int shot = 0; shot < 2; ++shot) {
            int G = tid + shot * 256;
            int row = G >> 2, kgs = G & 3;
            int kgg = kgs ^ ((row >> 1) & 3);
            size_t goffB = (size_t)(col0 + row) * K + k0 + kgg * 8;
            async_copy16(Bgh + goffB, Bth + shot * 2048 + wbase);
            if (SPLIT) async_copy16(Bgl + goffB, Btl + shot * 2048 + wbase);
            size_t goffA = (size_t)(row0 + row) * K + k0 + kgg * 8;
            async_copy16(Agh + goffA, Ath + shot * 2048 + wbase);
            if (SPLIT) async_copy16(Agl + goffA, Atl + shot * 2048 + wbase);
        }
        __syncthreads();

        bfrag ah[4], bh[4], al[4], bl[4];
#pragma unroll
        for (int i = 0; i < 4; ++i) {
            int m = wm + i * 16 + tn;
            int g = m * 4 + (q ^ ((m >> 1) & 3));
            ah[i] = *(const bfrag*)(Ath + g * 8);
            if (SPLIT) al[i] = *(const bfrag*)(Atl + g * 8);
        }
#pragma unroll
        for (int j = 0; j < 4; ++j) {
            int n = wn + j * 16 + tn;
            int g = n * 4 + (q ^ ((n >> 1) & 3));
            bh[j] = *(const bfrag*)(Bth + g * 8);
            if (SPLIT) bl[j] = *(const bfrag*)(Btl + g * 8);
        }
#pragma unroll
        for (int i = 0; i < 4; ++i)
#pragma unroll
            for (int j = 0; j < 4; ++j) {
                acc[i][j] = mfma_bf16(ah[i], bh[j], acc[i][j]);
                if (SPLIT) {
                    acc[i][j] = mfma_bf16(ah[i], bl[j], acc[i][j]);
                    acc[i][j] = mfma_bf16(al[i], bh[j], acc[i][j]);
                }
            }
        __syncthreads();
    }

#pragma unroll
    for (int i = 0; i < 4; ++i)
#pragma unroll
        for (int j = 0; j < 4; ++j)
#pragma unroll
            for (int rg = 0; rg < 4; ++rg) {
                int row = row0 + wm + i * 16 + q * 4 + rg;
                int col = col0 + wn + j * 16 + tn;
                C[(size_t)row * N + col] = acc[i][j][rg];
            }
}

// ---------------------------------------------------------------------------
// Fused restore GEMMs: one launch, grid (24, 32); bx>>3 selects Q/K/V.
// Q,K: split-precision (3 MFMA), epilogue -> bf16 hi/lo [bh][s][dh].
// V: single bf16, epilogue -> transposed [bh][dh][s].
// A[i][k] = h[i][k&63] * w[i][k>>6] built on the fly (fp32 sources).
// ---------------------------------------------------------------------------
__global__ __launch_bounds__(256) void restore_mega(
    const float* __restrict__ h_q, const float* __restrict__ wQ,
    const float* __restrict__ h_k, const float* __restrict__ wK,
    const float* __restrict__ h_v, const float* __restrict__ wV,
    const u16* __restrict__ Rqh, const u16* __restrict__ Rql,
    const u16* __restrict__ Rvh,
    u16* __restrict__ Qh, u16* __restrict__ Ql,
    u16* __restrict__ Kh, u16* __restrict__ Kl,
    u16* __restrict__ Vt)
{
    const int sel = blockIdx.x >> 3;          // 0=Q, 1=K, 2=V
    const bool split = (sel < 2);
    const float* hA = (sel == 0) ? h_q : (sel == 1) ? h_k : h_v;
    const float* wA = (sel == 0) ? wQ  : (sel == 1) ? wK  : wV;
    const u16* Bgh = split ? Rqh : Rvh;
    const u16* Bgl = Rql;
    u16* Ch = (sel == 0) ? Qh : (sel == 1) ? Kh : Vt;
    u16* Cl = (sel == 0) ? Ql : Kl;
    const int K = 2048;

    __shared__ u16 lds[16384];
    u16* Ath = lds;
    u16* Atl = lds + 4096;
    u16* Bth = lds + 8192;
    u16* Btl = lds + 12288;

    const int tid  = threadIdx.x;
    const int lane = tid & 63;
    const int wv   = tid >> 6;
    const int q    = lane >> 4;
    const int tn   = lane & 15;
    const int wm   = (wv >> 1) * 64;
    const int wn   = (wv & 1) * 64;
    const int row0 = blockIdx.y * 128;
    const int col0 = (blockIdx.x & 7) * 128;
    const int wbase = (tid & 192) * 8;

    f32x4 acc[4][4];
#pragma unroll
    for (int i = 0; i < 4; ++i)
#pragma unroll
        for (int j = 0; j < 4; ++j) acc[i][j] = 0.f;

    for (int k0 = 0; k0 < K; k0 += 32) {
#pragma unroll
        for (int shot = 0; shot < 2; ++shot) {
            int G = tid + shot * 256;
            int row = G >> 2, kgs = G & 3;
            int kgg = kgs ^ ((row >> 1) & 3);
            size_t goff = (size_t)(col0 + row) * K + k0 + kgg * 8;
            async_copy16(Bgh + goff, Bth + shot * 2048 + wbase);
            if (split) async_copy16(Bgl + goff, Btl + shot * 2048 + wbase);
        }
        {
            const int r = tid >> 1;
            float wmul = wA[(size_t)(row0 + r) * 32 + (k0 >> 6)];
#pragma unroll
            for (int gi = 0; gi < 2; ++gi) {
                int gg = (tid & 1) * 2 + gi;
                const float* sp = hA + (size_t)(row0 + r) * 64 + (k0 & 63) + gg * 8;
                float4 v0 = *(const float4*)sp;
                float4 v1 = *(const float4*)(sp + 4);
                float vv[8] = {v0.x, v0.y, v0.z, v0.w, v1.x, v1.y, v1.z, v1.w};
                u16x8 hi, lo;
#pragma unroll
                for (int e = 0; e < 8; ++e) {
                    float val = vv[e] * wmul;
                    u16 hb = f2bf(val);
                    hi[e] = hb;
                    lo[e] = f2bf(val - bf2f(hb));
                }
                int slot = r * 4 + (gg ^ ((r >> 1) & 3));
                *(u16x8*)(Ath + slot * 8) = hi;
                if (split) *(u16x8*)(Atl + slot * 8) = lo;
            }
        }
        __syncthreads();

        bfrag ah[4], bh[4], al[4], bl[4];
#pragma unroll
        for (int i = 0; i < 4; ++i) {
            int m = wm + i * 16 + tn;
            int g = m * 4 + (q ^ ((m >> 1) & 3));
            ah[i] = *(const bfrag*)(Ath + g * 8);
            if (split) al[i] = *(const bfrag*)(Atl + g * 8);
        }
#pragma unroll
        for (int j = 0; j < 4; ++j) {
            int n = wn + j * 16 + tn;
            int g = n * 4 + (q ^ ((n >> 1) & 3));
            bh[j] = *(const bfrag*)(Bth + g * 8);
            if (split) bl[j] = *(const bfrag*)(Btl + g * 8);
        }
#pragma unroll
        for (int i = 0; i < 4; ++i)
#pragma unroll
            for (int j = 0; j < 4; ++j) {
                acc[i][j] = mfma_bf16(ah[i], bh[j], acc[i][j]);
                if (split) {
                    acc[i][j] = mfma_bf16(ah[i], bl[j], acc[i][j]);
                    acc[i][j] = mfma_bf16(al[i], bh[j], acc[i][j]);
                }
            }
        __syncthreads();
    }

#pragma unroll
    for (int i = 0; i < 4; ++i)
#pragma unroll
        for (int j = 0; j < 4; ++j)
#pragma unroll
            for (int rg = 0; rg < 4; ++rg) {
                int row = row0 + wm + i * 16 + q * 4 + rg;
                int col = col0 + wn + j * 16 + tn;
                float v = acc[i][j][rg];
                if (sel < 2) {
                    size_t idx = (((size_t)(row >> 11) * 16 + (col >> 6)) << 17)
                               | ((size_t)(row & 2047) << 6) | (size_t)(col & 63);
                    u16 hb = f2bf(v);
                    Ch[idx] = hb;
                    Cl[idx] = f2bf(v - bf2f(hb));
                } else {
                    size_t idx = ((((size_t)(row >> 11) * 16 + (col >> 6)) * 64
                                  + (size_t)(col & 63)) << 11) | (size_t)(row & 2047);
                    Ch[idx] = f2bf(v);
                }
            }
}

// ---------------------------------------------------------------------------
// Mix: h1[bs,r] = sum_n w1[bs,n] * P[bs, n*64+r]  (optionally h2 with w2)
// ---------------------------------------------------------------------------
__global__ __launch_bounds__(256) void mix_kernel(const float* __restrict__ P,
                                                  const float* __restrict__ w1,
                                                  const float* __restrict__ w2,
                                                  float* __restrict__ h1,
                                                  float* __restrict__ h2,
                                                  int two)
{
    int tid = blockIdx.x * 256 + threadIdx.x;
    int bs = tid >> 6;
    int r  = tid & 63;
    const float* Pp = P + (size_t)bs * 2048 + r;
    float a = 0.f, b = 0.f;
#pragma unroll
    for (int n = 0; n < 32; ++n) {
        float p = Pp[n * 64];
        a = fmaf(w1[bs * 32 + n], p, a);
        if (two) b = fmaf(w2[bs * 32 + n], p, b);
    }
    h1[tid] = a;
    if (two) h2[tid] = b;
}

// ---------------------------------------------------------------------------
// K-split MFMA flash attention (flash-decoding style).
// Block = (bh, q-tile of 64, key-chunk of 256). Grid (256, 32): bx = qb*8+c,
// early-exit if c >= nchunks(qb) = (qb>>2)+1. Each block runs <=4 K-tiles of
// the R3 structure and writes UN-normalized partial O (bf16) + m,l (fp32).
// Compact slot: base f(qb) = qb + 2g(g-1) + r*g (g=qb>>2, r=qb&3); 144/bh.
// ---------------------------------------------------------------------------
template<int SHOTS>
__device__ __forceinline__ void stage_tile(u16* dst, const u16* src, int rowstride,
                                           int tid, int wuni)
{
#pragma unroll
    for (int shot = 0; shot < SHOTS; ++shot) {
        int sl = shot * 256 + tid;
        int m = sl >> 3, s = sl & 7, g = s ^ (m & 7);
        async_copy16(src + (size_t)m * rowstride + g * 8, dst + shot * 2048 + wuni);
    }
}

__global__ __launch_bounds__(256) void flash_part(const u16* __restrict__ Qh_g,
                                                  const u16* __restrict__ Ql_g,
                                                  const u16* __restrict__ Kh_g,
                                                  const u16* __restrict__ Kl_g,
                                                  const u16* __restrict__ Vt_g,
                                                  u16* __restrict__ Opart,
                                                  float* __restrict__ ml)
{
    const int bh = blockIdx.y;
    const int qb = blockIdx.x >> 3;
    const int c  = blockIdx.x & 7;
    const int g  = qb >> 2, rr = qb & 3;
    const int nch = g + 1;
    if (c >= nch) return;
    const int q0 = qb * 64;
    const int slot = bh * 144 + (qb + 2 * g * (g - 1) + rr * g) + c;

    const int tid = threadIdx.x;
    const int lane = tid & 63;
    const int wv = tid >> 6;
    const int q = lane >> 4;
    const int tn = lane & 15;
    const int wuni = (tid & 192) * 8;

    __shared__ u16 sQh[4096], sQl[4096], sKh[4096], sKl[4096], sVt[4096], sP[4096];

    const size_t qoff = ((size_t)bh * 2048 + q0) * 64;
    stage_tile<2>(sQh, Qh_g + qoff, 64, tid, wuni);
    stage_tile<2>(sQl, Ql_g + qoff, 64, tid, wuni);
    __syncthreads();

    bfrag qfh[2], qfl[2];
#pragma unroll
    for (int ks = 0; ks < 2; ++ks) {
        int m = wv * 16 + tn;
        int slt = (ks * 4 + q) ^ (m & 7);
        qfh[ks] = *(const bfrag*)(sQh + m * 64 + slt * 8);
        qfl[ks] = *(const bfrag*)(sQl + m * 64 + slt * 8);
    }

    float m_i[4], l_i[4];
    f32x4 acc_o[4];
#pragma unroll
    for (int ri = 0; ri < 4; ++ri) { m_i[ri] = -3.0e38f; l_i[ri] = 0.f; }
#pragma unroll
    for (int dt = 0; dt < 4; ++dt) acc_o[dt] = 0.f;

    const size_t kbase = (size_t)bh * 2048 * 64;
    const size_t vbase = (size_t)bh * 64 * 2048;
    const int kt_end = min(4 * c + 3, qb);

    for (int kt = 4 * c; kt <= kt_end; ++kt) {
        const int k0 = kt * 64;
        __syncthreads();
        stage_tile<2>(sKh, Kh_g + kbase + (size_t)k0 * 64, 64, tid, wuni);
        stage_tile<2>(sKl, Kl_g + kbase + (size_t)k0 * 64, 64, tid, wuni);
        stage_tile<2>(sVt, Vt_g + vbase + k0, 2048, tid, wuni);
        __syncthreads();

        // QK^T split precision
        f32x4 accs[4];
#pragma unroll
        for (int n = 0; n < 4; ++n) accs[n] = 0.f;
#pragma unroll
        for (int n = 0; n < 4; ++n) {
            int r = n * 16 + tn;
#pragma unroll
            for (int ks = 0; ks < 2; ++ks) {
                int slt = (ks * 4 + q) ^ (r & 7);
                bfrag kh = *(const bfrag*)(sKh + r * 64 + slt * 8);
                bfrag kl = *(const bfrag*)(sKl + r * 64 + slt * 8);
                accs[n] = mfma_bf16(qfh[ks], kh, accs[n]);
                accs[n] = mfma_bf16(qfh[ks], kl, accs[n]);
                accs[n] = mfma_bf16(qfl[ks], kh, accs[n]);
            }
        }
        const bool diag = (kt == qb);
#pragma unroll
        for (int n = 0; n < 4; ++n)
#pragma unroll
            for (int ri = 0; ri < 4; ++ri) {
                float v = accs[n][ri] * 0.125f;
                if (diag && (n * 16 + tn > wv * 16 + q * 4 + ri)) v = -3.0e38f;
                accs[n][ri] = v;
            }
        // online softmax (rows across 16-lane quads)
        float alpha[4], mnew[4], ssum[4];
#pragma unroll
        for (int ri = 0; ri < 4; ++ri) {
            float mx = fmaxf(fmaxf(accs[0][ri], accs[1][ri]),
                             fmaxf(accs[2][ri], accs[3][ri]));
#pragma unroll
            for (int xm = 1; xm < 16; xm <<= 1)
                mx = fmaxf(mx, __shfl_xor(mx, xm, 64));
            mnew[ri] = fmaxf(m_i[ri], mx);
            alpha[ri] = __expf(m_i[ri] - mnew[ri]);
            m_i[ri] = mnew[ri];
            ssum[ri] = 0.f;
        }
#pragma unroll
        for (int n = 0; n < 4; ++n)
#pragma unroll
            for (int ri = 0; ri < 4; ++ri) {
                float p = __expf(accs[n][ri] - mnew[ri]);
                ssum[ri] += p;
                int m = wv * 16 + q * 4 + ri;
                int cc = n * 16 + tn;
                int slt = (cc >> 3) ^ (m & 7);
                sP[m * 64 + slt * 8 + (cc & 7)] = f2bf(p);
            }
#pragma unroll
        for (int ri = 0; ri < 4; ++ri) {
            float sm = ssum[ri];
#pragma unroll
            for (int xm = 1; xm < 16; xm <<= 1)
                sm += __shfl_xor(sm, xm, 64);
            l_i[ri] = l_i[ri] * alpha[ri] + sm;
#pragma unroll
            for (int dt = 0; dt < 4; ++dt) acc_o[dt][ri] *= alpha[ri];
        }
        // PV (wave-local sP rows)
#pragma unroll
        for (int ks = 0; ks < 2; ++ks) {
            int m = wv * 16 + tn;
            int slt = (ks * 4 + q) ^ (m & 7);
            bfrag pf = *(const bfrag*)(sP + m * 64 + slt * 8);
#pragma unroll
            for (int dt = 0; dt < 4; ++dt) {
                int d = dt * 16 + tn;
                int vslt = (ks * 4 + q) ^ (d & 7);
                bfrag vf = *(const bfrag*)(sVt + d * 64 + vslt * 8);
                acc_o[dt] = mfma_bf16(pf, vf, acc_o[dt]);
            }
        }
    }

    // write partials: un-normalized O (bf16) + m,l (fp32)
#pragma unroll
    for (int dt = 0; dt < 4; ++dt)
#pragma unroll
        for (int ri = 0; ri < 4; ++ri) {
            int row = wv * 16 + q * 4 + ri;
            Opart[(size_t)slot * 4096 + row * 64 + dt * 16 + tn] = f2bf(acc_o[dt][ri]);
        }
    if (tn == 0) {
#pragma unroll
        for (int ri = 0; ri < 4; ++ri) {
            int row = wv * 16 + q * 4 + ri;
            ml[(size_t)slot * 128 + row]      = m_i[ri];
            ml[(size_t)slot * 128 + 64 + row] = l_i[ri];
        }
    }
}

// ---------------------------------------------------------------------------
// Combine partials: grid (32 qb, 32 bh), 256 thr. Thread: row=tid>>2,
// 16 cols at (tid&3)*16. O = sum_c Op_c*exp(m_c-m*), /= l*; write bf16 [bs][d].
// ---------------------------------------------------------------------------
__global__ __launch_bounds__(256) void flash_combine(const u16* __restrict__ Opart,
                                                     const float* __restrict__ ml,
                                                     u16* __restrict__ Am)
{
    const int qb = blockIdx.x, bh = blockIdx.y;
    const int g = qb >> 2, rr = qb & 3;
    const int nch = g + 1;
    const int base = bh * 144 + (qb + 2 * g * (g - 1) + rr * g);
    const int tid = threadIdx.x;
    const int row = tid >> 2;
    const int c0  = (tid & 3) * 16;

    float mstar = -3.0e38f;
    float mc[8];
#pragma unroll
    for (int c = 0; c < 8; ++c) {
        if (c < nch) {
            mc[c] = ml[(size_t)(base + c) * 128 + row];
            mstar = fmaxf(mstar, mc[c]);
        }
    }
    float lstar = 0.f, wc[8];
#pragma unroll
    for (int c = 0; c < 8; ++c) {
        if (c < nch) {
            wc[c] = __expf(mc[c] - mstar);
            lstar += ml[(size_t)(base + c) * 128 + 64 + row] * wc[c];
        }
    }
    float o[16];
#pragma unroll
    for (int j = 0; j < 16; ++j) o[j] = 0.f;
    for (int c = 0; c < nch; ++c) {
        const u16* p = Opart + (size_t)(base + c) * 4096 + row * 64 + c0;
        u16x8 v0 = *(const u16x8*)p;
        u16x8 v1 = *(const u16x8*)(p + 8);
#pragma unroll
        for (int j = 0; j < 8; ++j) {
            o[j]     = fmaf(bf2f(v0[j]), wc[c], o[j]);
            o[j + 8] = fmaf(bf2f(v1[j]), wc[c], o[j + 8]);
        }
    }
    float inv = 1.0f / lstar;
    int srow = qb * 64 + row;
    size_t obase = ((size_t)(bh >> 4) * 2048 + srow) * 1024
                 + (size_t)((bh & 15) * 64 + c0);
    u16x8 w0, w1;
#pragma unroll
    for (int j = 0; j < 8; ++j) {
        w0[j] = f2bf(o[j] * inv);
        w1[j] = f2bf(o[j + 8] * inv);
    }
    *(u16x8*)(Am + obase)     = w0;
    *(u16x8*)(Am + obase + 8) = w1;
}

// ---------------------------------------------------------------------------
extern "C" void kernel_launch(void* const* d_in, const int* in_sizes, int n_in,
                              void* d_out, int out_size, void* d_ws, size_t ws_size,
                              hipStream_t stream)
{
    const float* x     = (const float*)d_in[0];
    const float* wfqkQ = (const float*)d_in[1];
    const float* wfqkK = (const float*)d_in[2];
    const float* wfv   = (const float*)d_in[3];
    const float* wrqkQ = (const float*)d_in[4];
    const float* wrqkK = (const float*)d_in[5];
    const float* wrv   = (const float*)d_in[6];
    const float* f_qk  = (const float*)d_in[7];
    const float* f_v   = (const float*)d_in[8];
    const float* r_qk  = (const float*)d_in[9];
    const float* r_v   = (const float*)d_in[10];
    const float* W_O   = (const float*)d_in[11];
    float* out = (float*)d_out;

    const size_t MB = 1u << 20;
    char* w8 = (char*)d_ws;
    u16*  WOb   = (u16*)(w8 + 0);          //  2MB [1024][1024] (live to the end)
    u16*  FqkTh = (u16*)(w8 + 2  * MB);    //  4MB [2048][1024]
    u16*  FqkTl = (u16*)(w8 + 6  * MB);
    u16*  FvT   = (u16*)(w8 + 10 * MB);
    u16*  RqkTh = (u16*)(w8 + 14 * MB);    //  4MB [1024][2048]
    u16*  RqkTl = (u16*)(w8 + 18 * MB);
    u16*  RvT   = (u16*)(w8 + 22 * MB);
    float* h_q  = (float*)(w8 + 26 * MB);  //  1MB each
    float* h_k  = (float*)(w8 + 27 * MB);
    float* h_v  = (float*)(w8 + 28 * MB);
    u16*  x_hi  = (u16*)(w8 + 30 * MB);    //  8MB
    u16*  x_lo  = (u16*)(w8 + 38 * MB);
    float* P    = (float*)(w8 + 48 * MB);  // 32MB fp32 (dead after mix)
    u16*  Qh    = (u16*)(w8 + 48 * MB);    //  8MB each, [bh][s][dh] (over P)
    u16*  Ql    = (u16*)(w8 + 56 * MB);
    u16*  Kh    = (u16*)(w8 + 64 * MB);
    u16*  Kl    = (u16*)(w8 + 72 * MB);
    u16*  Vt    = (u16*)(w8 + 80 * MB);    //  8MB [bh][dh][s]
    u16*  Am    = (u16*)(w8 + 88 * MB);    //  8MB bf16 attn out
    // flash partials (reuse dead pre-restore region 2..46 MB):
    u16*  Opart = (u16*)(w8 + 2  * MB);    // 4608*4096*2B = 37.75MB -> ends ~39.75
    float* mlws = (float*)(w8 + 40 * MB);  // 4608*128*4B  =  2.36MB -> ends ~42.4

    dim3 blk(256);

    // casts / transposes
    cast_split<1><<<dim3(4096), blk, 0, stream>>>(x, x_hi, x_lo, 1024 * 1024);
    cast_split<0><<<dim3(1024), blk, 0, stream>>>(W_O, WOb, nullptr, 256 * 1024);
    transpose_cast<1><<<dim3(2, 32, 32), blk, 0, stream>>>(f_qk, FqkTh, FqkTl, 1024, 64, 1024);
    transpose_cast<0><<<dim3(2, 32, 32), blk, 0, stream>>>(f_v,  FvT,   nullptr, 1024, 64, 1024);
    transpose_cast<1><<<dim3(32, 64, 1), blk, 0, stream>>>(r_qk, RqkTh, RqkTl, 2048, 1024, 2048);
    transpose_cast<0><<<dim3(32, 64, 1), blk, 0, stream>>>(r_v,  RvT,   nullptr, 2048, 1024, 2048);

    // project + mix
    gemm_mfma<1><<<dim3(16, 32), blk, 0, stream>>>(x_hi, x_lo, FqkTh, FqkTl, P,
                                                   4096, 2048, 1024);
    mix_kernel<<<dim3(1024), blk, 0, stream>>>(P, wfqkQ, wfqkK, h_q, h_k, 1);
    gemm_mfma<0><<<dim3(16, 32), blk, 0, stream>>>(x_hi, nullptr, FvT, nullptr, P,
                                                   4096, 2048, 1024);
    mix_kernel<<<dim3(1024), blk, 0, stream>>>(P, wfv, nullptr, h_v, nullptr, 0);

    // fused restore -> bf16 attention operands
    restore_mega<<<dim3(24, 32), blk, 0, stream>>>(h_q, wrqkQ, h_k, wrqkK, h_v, wrv,
                                                   RqkTh, RqkTl, RvT,
                                                   Qh, Ql, Kh, Kl, Vt);

    // K-split flash attention: partials + combine
    flash_part<<<dim3(256, 32), blk, 0, stream>>>(Qh, Ql, Kh, Kl, Vt, Opart, mlws);
    flash_combine<<<dim3(32, 32), blk, 0, stream>>>(Opart, mlws, Am);

    // output projection
    gemm_mfma<0><<<dim3(8, 32), blk, 0, stream>>>(Am, nullptr, WOb, nullptr, out,
                                                  4096, 1024, 1024);
}